// Round 1
// 1139.748 us; speedup vs baseline: 1.0614x; 1.0614x over previous
//
#include <hip/hip_runtime.h>
#include <hip/hip_bf16.h>

#define B_   2
#define S_   4096
#define DM_  768
#define H_   12
#define D_   64
#define W_   256
#define NB_  16
#define DFF_ 3072
#define L_   2
#define QS_  3840
#define NEG_ (-1.0e9f)
#define GC_  16    // gattn chunks
#define QB_  64    // band attn queries per block
#define NCH_ 18    // band attn key chunks: (QB_ + 2*W_)/32

typedef long long ll;
typedef unsigned short u16;
typedef unsigned int   u32;

typedef __attribute__((ext_vector_type(8))) short bfrag;
typedef __attribute__((ext_vector_type(4))) float ffrag;
typedef __attribute__((address_space(1))) unsigned gu32;
typedef __attribute__((address_space(3))) unsigned lu32;

// ---------------- helpers ----------------
__device__ __forceinline__ float b2f(u16 u){ union{u32 i; float f;} x; x.i = ((u32)u)<<16; return x.f; }
__device__ __forceinline__ u16 f2b(float f){
  __hip_bfloat16 h = __float2bfloat16(f);
  union{__hip_bfloat16 h; u16 u;} x; x.h = h; return x.u;
}
__device__ __forceinline__ void unp8(uint4 u, float* f){
  union{u32 i; float v;} a;
  a.i = u.x<<16; f[0]=a.v; a.i = u.x&0xffff0000u; f[1]=a.v;
  a.i = u.y<<16; f[2]=a.v; a.i = u.y&0xffff0000u; f[3]=a.v;
  a.i = u.z<<16; f[4]=a.v; a.i = u.z&0xffff0000u; f[5]=a.v;
  a.i = u.w<<16; f[6]=a.v; a.i = u.w&0xffff0000u; f[7]=a.v;
}
__device__ __forceinline__ void gld16(const void* g, void* l){
  __builtin_amdgcn_global_load_lds((gu32*)g, (lu32*)l, 16, 0, 0);
}
__device__ __forceinline__ float bsum256(float v, float* s4){
  #pragma unroll
  for(int o=32;o>0;o>>=1) v += __shfl_down(v,o,64);
  int w = threadIdx.x>>6;
  __syncthreads();
  if((threadIdx.x&63)==0) s4[w]=v;
  __syncthreads();
  return s4[0]+s4[1]+s4[2]+s4[3];
}
__device__ __forceinline__ float bmax256(float v, float* s4){
  #pragma unroll
  for(int o=32;o>0;o>>=1) v = fmaxf(v,__shfl_down(v,o,64));
  int w = threadIdx.x>>6;
  __syncthreads();
  if((threadIdx.x&63)==0) s4[w]=v;
  __syncthreads();
  return fmaxf(fmaxf(s4[0],s4[1]),fmaxf(s4[2],s4[3]));
}
__device__ __forceinline__ float gelu_f(float x){
  return 0.5f*x*(1.0f+tanhf(0.7978845608028654f*(x+0.044715f*x*x*x)));
}

// ---------------- dtype detect: ln_e_s is all-ones ----------------
__global__ void k_detect(const void* les, int* flag){
  unsigned u = *(const unsigned*)les;
  *flag = (u == 0x3F803F80u) ? 1 : 0;
}

// ---------------- convert float input (f32 or bf16) to f32, with src elem offset ----------------
__global__ void k_cvt(const void* __restrict__ src, ll soff, float* __restrict__ dst, int n, const int* flag){
  int f = *flag;
  int i = blockIdx.x*256 + threadIdx.x;
  int st = gridDim.x*256;
  if(f){
    const u16* s = (const u16*)src + soff;
    for(; i<n; i+=st) dst[i] = b2f(s[i]);
  } else {
    const float* s = (const float*)src + soff;
    for(; i<n; i+=st) dst[i] = s[i];
  }
}

// ---------------- batched small converts ----------------
struct CvtArgs { const void* src[32]; float* dst[32]; int soff[32]; int n[32]; };
__global__ void k_cvts(CvtArgs a, const int* __restrict__ flag){
  int seg = blockIdx.y;
  int i = blockIdx.x*256 + threadIdx.x;
  if(i >= a.n[seg]) return;
  int f = *flag;
  float v = f ? b2f(((const u16*)a.src[seg])[a.soff[seg]+i])
              : ((const float*)a.src[seg])[a.soff[seg]+i];
  a.dst[seg][i] = v;
}

// ---------------- weight transpose: src[R][C] (f32/bf16) -> dst[C][R] bf16 ----------------
__global__ __launch_bounds__(256) void k_tw(const void* __restrict__ src, ll soff, u16* __restrict__ dst,
    int R, int C, const int* __restrict__ flag){
  __shared__ float tile[32][33];
  int f = *flag;
  int tx = threadIdx.x & 31, ty = threadIdx.x >> 5;
  int c = blockIdx.x*32 + tx;
  #pragma unroll
  for(int i=0;i<4;i++){
    int r = blockIdx.y*32 + ty + i*8;
    float v;
    if(f) v = b2f(((const u16*)src)[soff + (ll)r*C + c]);
    else  v = ((const float*)src)[soff + (ll)r*C + c];
    tile[ty + i*8][tx] = v;
  }
  __syncthreads();
  #pragma unroll
  for(int i=0;i<4;i++){
    int orow = blockIdx.x*32 + ty + i*8;
    int oc   = blockIdx.y*32 + tx;
    dst[(ll)orow*R + oc] = f2b(tile[tx][ty + i*8]);
  }
}

// batched 768x768 transposes
struct TwArgs { const void* src[14]; ll soff[14]; u16* dst[14]; };
__global__ __launch_bounds__(256) void k_tws(TwArgs a, const int* __restrict__ flag){
  __shared__ float tile[32][33];
  int z = blockIdx.z;
  const void* src = a.src[z]; ll soff = a.soff[z]; u16* dst = a.dst[z];
  int f = *flag;
  int tx = threadIdx.x & 31, ty = threadIdx.x >> 5;
  int c = blockIdx.x*32 + tx;
  #pragma unroll
  for(int i=0;i<4;i++){
    int r = blockIdx.y*32 + ty + i*8;
    float v;
    if(f) v = b2f(((const u16*)src)[soff + (ll)r*DM_ + c]);
    else  v = ((const float*)src)[soff + (ll)r*DM_ + c];
    tile[ty + i*8][tx] = v;
  }
  __syncthreads();
  #pragma unroll
  for(int i=0;i<4;i++){
    int orow = blockIdx.x*32 + ty + i*8;
    int oc   = blockIdx.y*32 + tx;
    dst[(ll)orow*DM_ + oc] = f2b(tile[tx][ty + i*8]);
  }
}

// ---------------- embedding gather + LN -> x (f32) + xb (bf16) ----------------
__global__ __launch_bounds__(256) void k_embed(const int* __restrict__ ids, const void* __restrict__ wemb,
    const float* __restrict__ pos, const float* __restrict__ es, const float* __restrict__ eb,
    float* __restrict__ x, u16* __restrict__ xb, const int* flag){
  __shared__ float s4[4];
  int tok = blockIdx.x;
  int s = tok & (S_-1);
  int t = threadIdx.x;
  int id = ids[tok];
  int f = *flag;
  float v[3];
  #pragma unroll
  for(int j=0;j<3;j++){
    int i = t + j*256;
    float we = f ? b2f(((const u16*)wemb)[(ll)id*DM_ + i])
                 : ((const float*)wemb)[(ll)id*DM_ + i];
    v[j] = we + pos[s*DM_ + i];
  }
  float mean = bsum256(v[0]+v[1]+v[2], s4) * (1.0f/DM_);
  float d0=v[0]-mean, d1=v[1]-mean, d2=v[2]-mean;
  float var = bsum256(d0*d0+d1*d1+d2*d2, s4) * (1.0f/DM_);
  float r = rsqrtf(var + 1e-5f);
  #pragma unroll
  for(int j=0;j<3;j++){
    int i = t + j*256;
    float o = (v[j]-mean)*r*es[i] + eb[i];
    x[(ll)tok*DM_ + i] = o;
    xb[(ll)tok*DM_ + i] = f2b(o);
  }
}

// ---------------- residual add + LN (in-place x) + bf16 copy ----------------
__global__ __launch_bounds__(256) void k_rln(float* __restrict__ x, const float* __restrict__ add,
    const float* __restrict__ sc, const float* __restrict__ bi, u16* __restrict__ xb){
  __shared__ float s4[4];
  int tok = blockIdx.x;
  int t = threadIdx.x;
  float v[3];
  #pragma unroll
  for(int j=0;j<3;j++){
    int i = t + j*256;
    v[j] = x[(ll)tok*DM_+i] + add[(ll)tok*DM_+i];
  }
  float mean = bsum256(v[0]+v[1]+v[2], s4) * (1.0f/DM_);
  float d0=v[0]-mean, d1=v[1]-mean, d2=v[2]-mean;
  float var = bsum256(d0*d0+d1*d1+d2*d2, s4) * (1.0f/DM_);
  float r = rsqrtf(var + 1e-5f);
  #pragma unroll
  for(int j=0;j<3;j++){
    int i = t + j*256;
    float o = (v[j]-mean)*r*sc[i] + bi[i];
    x[(ll)tok*DM_+i] = o;
    xb[(ll)tok*DM_+i] = f2b(o);
  }
}

// ---------------- bf16 MFMA GEMM: C[M,N] = A[M,K] @ Bt[N,K]^T + bias ----------------
template<int MODE>   // 0 = bf16 out, 1 = f32 out, 2 = bf16 out + gelu
__global__ __launch_bounds__(256) void k_mm(const u16* __restrict__ A, const u16* __restrict__ Bt,
    const float* __restrict__ bias, void* __restrict__ Cout, int M, int N, int K){
  __shared__ __align__(16) u16 As[128*32];
  __shared__ __align__(16) u16 Bs[128*32];
  int tid = threadIdx.x, wave = tid>>6, lane = tid&63;
  int m0 = blockIdx.y*128, n0 = blockIdx.x*128;
  int wm = (wave>>1)*64, wn = (wave&1)*64;
  ffrag acc[4][4];
  #pragma unroll
  for(int i=0;i<4;i++)
    #pragma unroll
    for(int j=0;j<4;j++) acc[i][j] = (ffrag){0.f,0.f,0.f,0.f};
  int lrow = lane>>2, lseg = (lane&3)*8;
  const u16* Ap0 = A  + (ll)(m0 + wave*32 + lrow)*K + lseg;
  const u16* Bp0 = Bt + (ll)(n0 + wave*32 + lrow)*K + lseg;
  u16* AsW0 = As + (wave*2+0)*512;
  u16* AsW1 = As + (wave*2+1)*512;
  u16* BsW0 = Bs + (wave*2+0)*512;
  u16* BsW1 = Bs + (wave*2+1)*512;
  int lane15 = lane&15, quad = lane>>4;
  const u16* ArA = As + (wm + lane15)*32 + quad*8;
  const u16* BrB = Bs + (wn + lane15)*32 + quad*8;
  for(int k0=0; k0<K; k0+=32){
    __syncthreads();
    gld16(Ap0 + k0,             AsW0);
    gld16(Ap0 + k0 + (ll)16*K,  AsW1);
    gld16(Bp0 + k0,             BsW0);
    gld16(Bp0 + k0 + (ll)16*K,  BsW1);
    __syncthreads();
    bfrag af[4], bf[4];
    #pragma unroll
    for(int i=0;i<4;i++) af[i] = *(const bfrag*)(ArA + i*512);
    #pragma unroll
    for(int i=0;i<4;i++) bf[i] = *(const bfrag*)(BrB + i*512);
    #pragma unroll
    for(int i=0;i<4;i++)
      #pragma unroll
      for(int j=0;j<4;j++)
        acc[i][j] = __builtin_amdgcn_mfma_f32_16x16x32_bf16(af[i], bf[j], acc[i][j], 0, 0, 0);
  }
  #pragma unroll
  for(int mi=0;mi<4;mi++){
    #pragma unroll
    for(int ni=0;ni<4;ni++){
      int col = n0 + wn + ni*16 + lane15;
      float bv = bias[col];
      #pragma unroll
      for(int r=0;r<4;r++){
        int row = m0 + wm + mi*16 + quad*4 + r;
        float c = acc[mi][ni][r] + bv;
        if(MODE==2) c = gelu_f(c);
        if(MODE==1) ((float*)Cout)[(ll)row*N + col] = c;
        else        ((u16*)Cout)[(ll)row*N + col] = f2b(c);
      }
    }
  }
}

// ---------------- qg = x[:,0] @ Wqg + bqg ----------------
__global__ __launch_bounds__(256) void k_qg(const float* __restrict__ x, const u16* __restrict__ Wt,
    const float* __restrict__ bg, float* __restrict__ qg){
  int b = blockIdx.y;
  int nn = blockIdx.x*256 + threadIdx.x;
  __shared__ float xs[DM_];
  int t = threadIdx.x;
  #pragma unroll
  for(int j=0;j<3;j++) xs[t + j*256] = x[(ll)(b*S_)*DM_ + t + j*256];
  __syncthreads();
  const uint4* wr = (const uint4*)(Wt + (ll)nn*DM_);
  float acc = bg[nn];
  #pragma unroll 4
  for(int g=0; g<96; g++){
    float tf[8]; unp8(wr[g], tf);
    #pragma unroll
    for(int e=0;e<8;e++) acc = fmaf(xs[g*8+e], tf[e], acc);
  }
  qg[b*DM_ + nn] = acc;
}

// ---------------- banded attention: MFMA flash, 64 queries/block, 4 waves x 16 queries ----------------
// grid: dim3(S_/QB_, H_, B_); 18 chunks of 32 keys covering [q0-W, q0+QB_+W)
__global__ __launch_bounds__(256) void k_band(const u16* __restrict__ qb, const u16* __restrict__ kb,
    const u16* __restrict__ vb, const int* __restrict__ am, u16* __restrict__ aout){
  int nq = blockIdx.x, h = blockIdx.y, b = blockIdx.z;
  int q0 = nq*QB_;
  int tid = threadIdx.x;
  int wave = tid>>6, lane = tid&63, lane15 = lane&15, quad = lane>>4;
  int wq = wave*16;
  __shared__ __align__(16) u16 Ks[32*72];     // [key][d], stride 72
  __shared__ __align__(16) u16 Vt[64*40];     // [d][key], stride 40
  __shared__ __align__(16) u16 Ps[4][16*40];  // per-wave P [q][key], stride 40, col^=8*quad(row)
  __shared__ float k0f[64];
  __shared__ float v0f[64];
  __shared__ float cok[32];
  const int kbase = q0 - W_;
  const int am0 = am[b*S_];
  bfrag aq[2];
  {
    const u16* qbase = qb + ((ll)(b*S_ + q0 + wq + lane15))*QS_ + h*64 + quad*8;
    aq[0] = *(const bfrag*)(qbase);
    aq[1] = *(const bfrag*)(qbase + 32);
  }
  if(tid < 64){
    k0f[tid] = b2f(kb[(ll)(b*S_)*QS_ + h*64 + tid]);
    v0f[tid] = b2f(vb[(ll)(b*S_)*QS_ + h*64 + tid]);
  }
  ffrag ao[4];
  #pragma unroll
  for(int j=0;j<4;j++) ao[j] = (ffrag){0.f,0.f,0.f,0.f};
  float ms[4], ls[4];
  #pragma unroll
  for(int i=0;i<4;i++){ ms[i] = -INFINITY; ls[i] = 0.f; }

  #pragma unroll 1
  for(int c=0;c<NCH_;c++){
    __syncthreads();
    {
      // K stage: key = tid>>3 (0..31), seg = tid&7, contiguous 16B writes
      int key = tid>>3, seg = tid&7;
      int kp = kbase + c*32 + key;
      uint4 kvec = make_uint4(0,0,0,0);
      if((unsigned)kp < (unsigned)S_)
        kvec = *(const uint4*)(kb + ((ll)(b*S_+kp))*QS_ + h*64 + seg*8);
      *(uint4*)&Ks[key*72 + seg*8] = kvec;
      // V stage transposed: each thread gathers 8 keys of one d (coalesced 128B/wave
      // ushort loads), writes one contiguous 16B row-segment of Vt (conflict-free).
      int kpv = kbase + c*32 + wave*8;
      union { u16 s[8]; uint4 v; } vu;
      #pragma unroll
      for(int j=0;j<8;j++){
        int kp2 = kpv + j;
        vu.s[j] = ((unsigned)kp2 < (unsigned)S_) ? vb[((ll)(b*S_+kp2))*QS_ + h*64 + lane] : (u16)0;
      }
      *(uint4*)&Vt[lane*40 + wave*8] = vu.v;
      if(tid < 32){
        int kp2 = kbase + c*32 + tid;
        cok[tid] = ((kp2>=1) && (kp2<S_) && (am[b*S_+kp2]>0)) ? 0.f : NEG_;
      }
    }
    __syncthreads();
    ffrag as_[2];
    as_[0] = (ffrag){0.f,0.f,0.f,0.f};
    as_[1] = (ffrag){0.f,0.f,0.f,0.f};
    #pragma unroll
    for(int ni=0;ni<2;ni++){
      #pragma unroll
      for(int kc=0;kc<2;kc++){
        bfrag bk = *(const bfrag*)&Ks[(ni*16+lane15)*72 + kc*32 + quad*8];
        as_[ni] = __builtin_amdgcn_mfma_f32_16x16x32_bf16(aq[kc], bk, as_[ni], 0, 0, 0);
      }
    }
    float c0 = cok[lane15], c1 = cok[16+lane15];
    int jg0 = c*32 + lane15, jg1 = jg0 + 16;
    #pragma unroll
    for(int reg=0;reg<4;reg++){
      int qloc = wq + quad*4 + reg;
      float s0 = ((unsigned)(jg0 - qloc) <= 512u) ? as_[0][reg]*0.125f + c0 : NEG_;
      float s1 = ((unsigned)(jg1 - qloc) <= 512u) ? as_[1][reg]*0.125f + c1 : NEG_;
      float cm = fmaxf(s0, s1);
      cm = fmaxf(cm, __shfl_xor(cm,1));
      cm = fmaxf(cm, __shfl_xor(cm,2));
      cm = fmaxf(cm, __shfl_xor(cm,4));
      cm = fmaxf(cm, __shfl_xor(cm,8));
      float mn = fmaxf(ms[reg], cm);
      float al = __expf(ms[reg] - mn);
      float p0 = __expf(s0 - mn), p1 = __expf(s1 - mn);
      float rs = p0 + p1;
      rs += __shfl_xor(rs,1); rs += __shfl_xor(rs,2);
      rs += __shfl_xor(rs,4); rs += __shfl_xor(rs,8);
      ls[reg] = ls[reg]*al + rs;
      ms[reg] = mn;
      #pragma unroll
      for(int nt=0;nt<4;nt++) ao[nt][reg] *= al;
      int prow = quad*4 + reg;
      Ps[wave][prow*40 + (lane15 ^ (quad*8))]        = f2b(p0);
      Ps[wave][prow*40 + ((16 + lane15) ^ (quad*8))] = f2b(p1);
    }
    bfrag bv[4];
    #pragma unroll
    for(int nt=0;nt<4;nt++) bv[nt] = *(const bfrag*)&Vt[(nt*16+lane15)*40 + quad*8];
    int rperm = ((lane15>>2)&3)*8;
    bfrag ap = *(const bfrag*)&Ps[wave][lane15*40 + ((quad*8) ^ rperm)];
    #pragma unroll
    for(int nt=0;nt<4;nt++)
      ao[nt] = __builtin_amdgcn_mfma_f32_16x16x32_bf16(ap, bv[nt], ao[nt], 0, 0, 0);
  }
  float k0v[16];
  #pragma unroll
  for(int kc=0;kc<2;kc++)
    #pragma unroll
    for(int j=0;j<8;j++) k0v[kc*8+j] = k0f[kc*32 + quad*8 + j];
  float cokg = (am0>0) ? 0.f : NEG_;
  float sgm;
  {
    float d = 0.f;
    #pragma unroll
    for(int kc=0;kc<2;kc++)
      #pragma unroll
      for(int j=0;j<8;j++)
        d = fmaf(b2f((u16)aq[kc][j]), k0v[kc*8+j], d);
    d += __shfl_xor(d,16);
    d += __shfl_xor(d,32);
    sgm = d*0.125f + cokg;
  }
  float v0v[4];
  #pragma unroll
  for(int nt=0;nt<4;nt++) v0v[nt] = v0f[nt*16 + lane15];
  #pragma unroll
  for(int reg=0;reg<4;reg++){
    float sg = __shfl(sgm, (quad<<4) + quad*4 + reg);
    float mn = fmaxf(ms[reg], sg);
    float al = __expf(ms[reg] - mn);
    float pg = __expf(sg - mn);
    float inv = 1.f / (ls[reg]*al + pg);
    #pragma unroll
    for(int nt=0;nt<4;nt++)
      ao[nt][reg] = (ao[nt][reg]*al + pg*v0v[nt]) * inv;
  }
  u16* obase = aout + ((ll)(b*S_ + q0 + wq + quad*4))*DM_ + h*64 + lane15;
  #pragma unroll
  for(int reg=0;reg<4;reg++)
    #pragma unroll
    for(int nt=0;nt<4;nt++)
      obase[(ll)reg*DM_ + nt*16] = f2b(ao[nt][reg]);
}

// ---------------- global-token attention, stage 1: per-chunk partials ----------------
// part[b][h][chunk] = { m_c, l_c, o_c[64] }  (66 floats)
__global__ __launch_bounds__(256) void k_gattn1(const float* __restrict__ qg, const u16* __restrict__ kg,
    const u16* __restrict__ vg, const int* __restrict__ am, float* __restrict__ part){
  int ck = blockIdx.x, h = blockIdx.y, b = blockIdx.z;
  int t = threadIdx.x;
  __shared__ float s4[4];
  __shared__ float qgs[64];
  __shared__ float ps[256];
  __shared__ float obuf[4][64];
  if(t < 64) qgs[t] = qg[b*DM_ + h*64 + t];
  __syncthreads();
  int s = ck*256 + t;
  const uint4* kr = (const uint4*)(kg + (ll)(b*S_+s)*QS_ + h*64);
  float d = 0.f;
  #pragma unroll
  for(int g=0; g<8; g++){
    float tf[8]; unp8(kr[g], tf);
    #pragma unroll
    for(int e=0;e<8;e++) d = fmaf(qgs[g*8+e], tf[e], d);
  }
  float sc = (am[b*S_+s] > 0) ? d*0.125f : NEG_;
  float m_c = bmax256(sc, s4);
  float p = __expf(sc - m_c);
  float l_c = bsum256(p, s4);
  ps[t] = p;
  __syncthreads();
  // o_c[d] = sum_t p_t * v[t][d]; thread (grp,dd) covers 64 positions of group grp
  int dd = t & 63, grp = t >> 6;
  float acc = 0.f;
  const u16* vbase = vg + (ll)(b*S_ + ck*256 + grp*64)*QS_ + h*64 + dd;
  #pragma unroll 8
  for(int j=0;j<64;j++)
    acc = fmaf(ps[grp*64+j], b2f(vbase[(ll)j*QS_]), acc);
  obuf[grp][dd] = acc;
  __syncthreads();
  if(t < 64){
    float o = obuf[0][t] + obuf[1][t] + obuf[2][t] + obuf[3][t];
    float* pp = part + ((ll)(b*H_+h)*GC_ + ck)*66;
    if(t == 0){ pp[0] = m_c; pp[1] = l_c; }
    pp[2+t] = o;
  }
}

// ---------------- global-token attention, stage 2: combine chunks -> aout row 0 ----------------
__global__ void k_gattn2(const float* __restrict__ part, u16* __restrict__ aout){
  int h = blockIdx.x, b = blockIdx.y;
  int t = threadIdx.x;   // 64 threads
  const float* pp = part + ((ll)(b*H_+h)*GC_)*66;
  float m = -INFINITY;
  #pragma unroll
  for(int c=0;c<GC_;c++) m = fmaxf(m, pp[c*66]);
  float l = 0.f, o = 0.f;
  #pragma unroll
  for(int c=0;c<GC_;c++){
    float w = __expf(pp[c*66] - m);
    l += pp[c*66+1]*w;
    o += pp[c*66+2+t]*w;
  }
  aout[(ll)(b*S_)*DM_ + h*64 + t] = f2b(o/l);
}

// ---------------- classifier ----------------
__global__ __launch_bounds__(256) void k_cls(const float* __restrict__ x, const float* __restrict__ Wc,
    const float* __restrict__ bc, void* out, const int* flag){
  __shared__ float s4[4];
  int t = threadIdx.x;
  float a00=0,a01=0,a10=0,a11=0;
  for(int k=t;k<DM_;k+=256){
    float w0 = Wc[k*2], w1 = Wc[k*2+1];
    float x0 = x[k];
    float x1 = x[(ll)S_*DM_ + k];
    a00 = fmaf(x0,w0,a00); a01 = fmaf(x0,w1,a01);
    a10 = fmaf(x1,w0,a10); a11 = fmaf(x1,w1,a11);
  }
  float r00 = bsum256(a00,s4);
  float r01 = bsum256(a01,s4);
  float r10 = bsum256(a10,s4);
  float r11 = bsum256(a11,s4);
  if(t==0){
    float o[4] = {r00+bc[0], r01+bc[1], r10+bc[0], r11+bc[1]};
    if(*flag){
      __hip_bfloat16* ob = (__hip_bfloat16*)out;
      for(int i=0;i<4;i++) ob[i] = __float2bfloat16(o[i]);
    } else {
      float* of = (float*)out;
      for(int i=0;i<4;i++) of[i] = o[i];
    }
  }
}

extern "C" void kernel_launch(void* const* d_in, const int* in_sizes, int n_in,
                              void* d_out, int out_size, void* d_ws, size_t ws_size,
                              hipStream_t stream){
  char* wsb = (char*)d_ws;
  size_t off = 0;
  auto alloc = [&](size_t bytes)->size_t{ off = (off + 255) & ~(size_t)255; size_t r = off; off += bytes; return r; };
  const size_t TOK = (size_t)B_*S_;
  size_t P_flag = alloc(16);
  size_t P_pos  = alloc((size_t)S_*DM_*4);
  size_t P_les  = alloc(DM_*4), P_leb = alloc(DM_*4);
  size_t P_bqkv = alloc((size_t)L_*QS_*4);
  size_t P_bqg  = alloc((size_t)L_*DM_*4);
  size_t P_bo   = alloc((size_t)L_*DM_*4);
  size_t P_b1   = alloc((size_t)L_*DFF_*4);
  size_t P_b2   = alloc((size_t)L_*DM_*4);
  size_t P_l1s  = alloc((size_t)L_*DM_*4), P_l1b = alloc((size_t)L_*DM_*4);
  size_t P_l2s  = alloc((size_t)L_*DM_*4), P_l2b = alloc((size_t)L_*DM_*4);
  size_t P_Wc   = alloc(DM_*2*4), P_bc = alloc(64);
  size_t P_qgb  = alloc((size_t)B_*DM_*4);
  size_t P_part = alloc((size_t)B_*H_*GC_*66*4);
  size_t P_Wqkvt= alloc((size_t)L_*QS_*DM_*2);
  size_t P_Wqgt = alloc((size_t)L_*DM_*DM_*2);
  size_t P_Wot  = alloc((size_t)L_*DM_*DM_*2);
  size_t P_W1t  = alloc((size_t)L_*DM_*DFF_*2);
  size_t P_W2t  = alloc((size_t)L_*DFF_*DM_*2);
  size_t P_x    = alloc(TOK*DM_*4);
  size_t P_tmp  = alloc(TOK*DM_*4);
  size_t P_xb   = alloc(TOK*DM_*2);
  size_t P_qkv  = alloc(TOK*QS_*2);
  size_t P_aout = alloc(TOK*DM_*2);
  size_t P_h    = alloc(TOK*DFF_*2);

  int* flag = (int*)(wsb + P_flag);
  #define FP(o) ((float*)(wsb + (o)))
  #define HP(o) ((u16*)(wsb + (o)))

  k_detect<<<1,1,0,stream>>>(d_in[4], flag);

  k_cvt<<<2048,256,0,stream>>>(d_in[3], 0, FP(P_pos), S_*DM_, flag);

  {
    CvtArgs ca{};
    int ns = 0;
    auto addcv = [&](int idx, size_t dstoff, int soff, int nelem){
      ca.src[ns] = d_in[idx]; ca.dst[ns] = FP(dstoff); ca.soff[ns] = soff; ca.n[ns] = nelem; ns++;
    };
    addcv(4, P_les, 0, DM_); addcv(5, P_leb, 0, DM_);
    addcv(28, P_Wc, 0, DM_*2); addcv(29, P_bc, 0, 2);
    const int bidx[5] = {7,9,11,15,17};
    for(int l=0;l<L_;l++){
      for(int s=0;s<5;s++) addcv(bidx[s], P_bqkv + ((size_t)l*QS_ + s*DM_)*4, l*DM_, DM_);
      addcv(13, P_bqg + (size_t)l*DM_*4,  l*DM_,  DM_);
      addcv(19, P_bo  + (size_t)l*DM_*4,  l*DM_,  DM_);
      addcv(23, P_b1  + (size_t)l*DFF_*4, l*DFF_, DFF_);
      addcv(25, P_b2  + (size_t)l*DM_*4,  l*DM_,  DM_);
      addcv(20, P_l1s + (size_t)l*DM_*4,  l*DM_,  DM_);
      addcv(21, P_l1b + (size_t)l*DM_*4,  l*DM_,  DM_);
      addcv(26, P_l2s + (size_t)l*DM_*4,  l*DM_,  DM_);
      addcv(27, P_l2b + (size_t)l*DM_*4,  l*DM_,  DM_);
    }
    for(int s2=ns; s2<32; s2++){ ca.src[s2]=d_in[4]; ca.dst[s2]=FP(P_les); ca.soff[s2]=0; ca.n[s2]=0; }
    k_cvts<<<dim3(12, ns),256,0,stream>>>(ca, flag);
  }

  {
    TwArgs ta{};
    int nt_ = 0;
    const int widx[5] = {6,8,10,14,16};
    for(int l=0;l<L_;l++){
      for(int s=0;s<5;s++){
        ta.src[nt_] = d_in[widx[s]]; ta.soff[nt_] = (ll)l*DM_*DM_;
        ta.dst[nt_] = HP(P_Wqkvt) + (size_t)l*QS_*DM_ + (size_t)s*DM_*DM_; nt_++;
      }
      ta.src[nt_] = d_in[12]; ta.soff[nt_] = (ll)l*DM_*DM_;
      ta.dst[nt_] = HP(P_Wqgt) + (size_t)l*DM_*DM_; nt_++;
      ta.src[nt_] = d_in[18]; ta.soff[nt_] = (ll)l*DM_*DM_;
      ta.dst[nt_] = HP(P_Wot) + (size_t)l*DM_*DM_; nt_++;
    }
    k_tws<<<dim3(24,24,14),256,0,stream>>>(ta, flag);
  }
  for(int l=0;l<L_;l++){
    k_tw<<<dim3(DFF_/32, DM_/32),256,0,stream>>>(d_in[22], (ll)l*DM_*DFF_,
        HP(P_W1t) + (size_t)l*DFF_*DM_, DM_, DFF_, flag);
    k_tw<<<dim3(DM_/32, DFF_/32),256,0,stream>>>(d_in[24], (ll)l*DFF_*DM_,
        HP(P_W2t) + (size_t)l*DM_*DFF_, DFF_, DM_, flag);
  }

  const int* am = (const int*)d_in[1];
  k_embed<<<(int)TOK,256,0,stream>>>((const int*)d_in[0], d_in[2], FP(P_pos), FP(P_les), FP(P_leb),
                                     FP(P_x), HP(P_xb), flag);
  for(int l=0;l<L_;l++){
    const u16* Wqkvt_l = HP(P_Wqkvt) + (size_t)l*QS_*DM_;
    k_mm<0><<<dim3(QS_/128, TOK/128),256,0,stream>>>(HP(P_xb), Wqkvt_l, FP(P_bqkv) + (size_t)l*QS_,
        HP(P_qkv), (int)TOK, QS_, DM_);
    k_qg<<<dim3(3,B_),256,0,stream>>>(FP(P_x), HP(P_Wqgt) + (size_t)l*DM_*DM_, FP(P_bqg) + (size_t)l*DM_, FP(P_qgb));
    k_band<<<dim3(S_/QB_,H_,B_),256,0,stream>>>(HP(P_qkv), HP(P_qkv)+DM_, HP(P_qkv)+2*DM_, am, HP(P_aout));
    k_gattn1<<<dim3(GC_,H_,B_),256,0,stream>>>(FP(P_qgb), HP(P_qkv)+3*DM_, HP(P_qkv)+4*DM_, am, FP(P_part));
    k_gattn2<<<dim3(H_,B_),64,0,stream>>>(FP(P_part), HP(P_aout));
    k_mm<1><<<dim3(DM_/128, TOK/128),256,0,stream>>>(HP(P_aout), HP(P_Wot) + (size_t)l*DM_*DM_,
        FP(P_bo) + (size_t)l*DM_, FP(P_tmp), (int)TOK, DM_, DM_);
    k_rln<<<(int)TOK,256,0,stream>>>(FP(P_x), FP(P_tmp), FP(P_l1s) + (size_t)l*DM_, FP(P_l1b) + (size_t)l*DM_, HP(P_xb));
    k_mm<2><<<dim3(DFF_/128, TOK/128),256,0,stream>>>(HP(P_xb), HP(P_W1t) + (size_t)l*DFF_*DM_,
        FP(P_b1) + (size_t)l*DFF_, HP(P_h), (int)TOK, DFF_, DM_);
    k_mm<1><<<dim3(DM_/128, TOK/128),256,0,stream>>>(HP(P_h), HP(P_W2t) + (size_t)l*DM_*DFF_,
        FP(P_b2) + (size_t)l*DM_, FP(P_tmp), (int)TOK, DM_, DFF_);
    k_rln<<<(int)TOK,256,0,stream>>>(FP(P_x), FP(P_tmp), FP(P_l2s) + (size_t)l*DM_, FP(P_l2b) + (size_t)l*DM_, HP(P_xb));
  }
  k_cls<<<1,256,0,stream>>>(FP(P_x), FP(P_Wc), FP(P_bc), d_out, flag);
}

// Round 2
// 1048.405 us; speedup vs baseline: 1.1538x; 1.0871x over previous
//
#include <hip/hip_runtime.h>
#include <hip/hip_bf16.h>

#define B_   2
#define S_   4096
#define DM_  768
#define H_   12
#define D_   64
#define W_   256
#define NB_  16
#define DFF_ 3072
#define L_   2
#define QS_  3840
#define NEG_ (-1.0e9f)
#define GC_  16    // gattn chunks
#define QB_  64    // band attn queries per block
#define NCH_ 18    // band attn key chunks: (QB_ + 2*W_)/32

typedef long long ll;
typedef unsigned short u16;
typedef unsigned int   u32;

typedef __attribute__((ext_vector_type(8))) short bfrag;
typedef __attribute__((ext_vector_type(4))) float ffrag;
typedef __attribute__((address_space(1))) unsigned gu32;
typedef __attribute__((address_space(3))) unsigned lu32;

// ---------------- helpers ----------------
__device__ __forceinline__ float b2f(u16 u){ union{u32 i; float f;} x; x.i = ((u32)u)<<16; return x.f; }
__device__ __forceinline__ u16 f2b(float f){
  __hip_bfloat16 h = __float2bfloat16(f);
  union{__hip_bfloat16 h; u16 u;} x; x.h = h; return x.u;
}
__device__ __forceinline__ void unp8(uint4 u, float* f){
  union{u32 i; float v;} a;
  a.i = u.x<<16; f[0]=a.v; a.i = u.x&0xffff0000u; f[1]=a.v;
  a.i = u.y<<16; f[2]=a.v; a.i = u.y&0xffff0000u; f[3]=a.v;
  a.i = u.z<<16; f[4]=a.v; a.i = u.z&0xffff0000u; f[5]=a.v;
  a.i = u.w<<16; f[6]=a.v; a.i = u.w&0xffff0000u; f[7]=a.v;
}
__device__ __forceinline__ void gld16(const void* g, void* l){
  __builtin_amdgcn_global_load_lds((gu32*)g, (lu32*)l, 16, 0, 0);
}
__device__ __forceinline__ float bsum256(float v, float* s4){
  #pragma unroll
  for(int o=32;o>0;o>>=1) v += __shfl_down(v,o,64);
  int w = threadIdx.x>>6;
  __syncthreads();
  if((threadIdx.x&63)==0) s4[w]=v;
  __syncthreads();
  return s4[0]+s4[1]+s4[2]+s4[3];
}
__device__ __forceinline__ float bmax256(float v, float* s4){
  #pragma unroll
  for(int o=32;o>0;o>>=1) v = fmaxf(v,__shfl_down(v,o,64));
  int w = threadIdx.x>>6;
  __syncthreads();
  if((threadIdx.x&63)==0) s4[w]=v;
  __syncthreads();
  return fmaxf(fmaxf(s4[0],s4[1]),fmaxf(s4[2],s4[3]));
}
__device__ __forceinline__ float gelu_f(float x){
  return 0.5f*x*(1.0f+tanhf(0.7978845608028654f*(x+0.044715f*x*x*x)));
}

// ---------------- dtype detect: ln_e_s is all-ones ----------------
__global__ void k_detect(const void* les, int* flag){
  unsigned u = *(const unsigned*)les;
  *flag = (u == 0x3F803F80u) ? 1 : 0;
}

// ---------------- convert float input (f32 or bf16) to f32, with src elem offset ----------------
__global__ void k_cvt(const void* __restrict__ src, ll soff, float* __restrict__ dst, int n, const int* flag){
  int f = *flag;
  int i = blockIdx.x*256 + threadIdx.x;
  int st = gridDim.x*256;
  if(f){
    const u16* s = (const u16*)src + soff;
    for(; i<n; i+=st) dst[i] = b2f(s[i]);
  } else {
    const float* s = (const float*)src + soff;
    for(; i<n; i+=st) dst[i] = s[i];
  }
}

// ---------------- batched small converts ----------------
struct CvtArgs { const void* src[32]; float* dst[32]; int soff[32]; int n[32]; };
__global__ void k_cvts(CvtArgs a, const int* __restrict__ flag){
  int seg = blockIdx.y;
  int i = blockIdx.x*256 + threadIdx.x;
  if(i >= a.n[seg]) return;
  int f = *flag;
  float v = f ? b2f(((const u16*)a.src[seg])[a.soff[seg]+i])
              : ((const float*)a.src[seg])[a.soff[seg]+i];
  a.dst[seg][i] = v;
}

// ---------------- weight transpose: src[R][C] (f32/bf16) -> dst[C][R] bf16 ----------------
__global__ __launch_bounds__(256) void k_tw(const void* __restrict__ src, ll soff, u16* __restrict__ dst,
    int R, int C, const int* __restrict__ flag){
  __shared__ float tile[32][33];
  int f = *flag;
  int tx = threadIdx.x & 31, ty = threadIdx.x >> 5;
  int c = blockIdx.x*32 + tx;
  #pragma unroll
  for(int i=0;i<4;i++){
    int r = blockIdx.y*32 + ty + i*8;
    float v;
    if(f) v = b2f(((const u16*)src)[soff + (ll)r*C + c]);
    else  v = ((const float*)src)[soff + (ll)r*C + c];
    tile[ty + i*8][tx] = v;
  }
  __syncthreads();
  #pragma unroll
  for(int i=0;i<4;i++){
    int orow = blockIdx.x*32 + ty + i*8;
    int oc   = blockIdx.y*32 + tx;
    dst[(ll)orow*R + oc] = f2b(tile[tx][ty + i*8]);
  }
}

// batched 768x768 transposes
struct TwArgs { const void* src[14]; ll soff[14]; u16* dst[14]; };
__global__ __launch_bounds__(256) void k_tws(TwArgs a, const int* __restrict__ flag){
  __shared__ float tile[32][33];
  int z = blockIdx.z;
  const void* src = a.src[z]; ll soff = a.soff[z]; u16* dst = a.dst[z];
  int f = *flag;
  int tx = threadIdx.x & 31, ty = threadIdx.x >> 5;
  int c = blockIdx.x*32 + tx;
  #pragma unroll
  for(int i=0;i<4;i++){
    int r = blockIdx.y*32 + ty + i*8;
    float v;
    if(f) v = b2f(((const u16*)src)[soff + (ll)r*DM_ + c]);
    else  v = ((const float*)src)[soff + (ll)r*DM_ + c];
    tile[ty + i*8][tx] = v;
  }
  __syncthreads();
  #pragma unroll
  for(int i=0;i<4;i++){
    int orow = blockIdx.x*32 + ty + i*8;
    int oc   = blockIdx.y*32 + tx;
    dst[(ll)orow*DM_ + oc] = f2b(tile[tx][ty + i*8]);
  }
}

// ---------------- embedding gather + LN -> x (f32) + xb (bf16) ----------------
__global__ __launch_bounds__(256) void k_embed(const int* __restrict__ ids, const void* __restrict__ wemb,
    const float* __restrict__ pos, const float* __restrict__ es, const float* __restrict__ eb,
    float* __restrict__ x, u16* __restrict__ xb, const int* flag){
  __shared__ float s4[4];
  int tok = blockIdx.x;
  int s = tok & (S_-1);
  int t = threadIdx.x;
  int id = ids[tok];
  int f = *flag;
  float v[3];
  #pragma unroll
  for(int j=0;j<3;j++){
    int i = t + j*256;
    float we = f ? b2f(((const u16*)wemb)[(ll)id*DM_ + i])
                 : ((const float*)wemb)[(ll)id*DM_ + i];
    v[j] = we + pos[s*DM_ + i];
  }
  float mean = bsum256(v[0]+v[1]+v[2], s4) * (1.0f/DM_);
  float d0=v[0]-mean, d1=v[1]-mean, d2=v[2]-mean;
  float var = bsum256(d0*d0+d1*d1+d2*d2, s4) * (1.0f/DM_);
  float r = rsqrtf(var + 1e-5f);
  #pragma unroll
  for(int j=0;j<3;j++){
    int i = t + j*256;
    float o = (v[j]-mean)*r*es[i] + eb[i];
    x[(ll)tok*DM_ + i] = o;
    xb[(ll)tok*DM_ + i] = f2b(o);
  }
}

// ---------------- residual add + LN (in-place x) + bf16 copy ----------------
__global__ __launch_bounds__(256) void k_rln(float* __restrict__ x, const float* __restrict__ add,
    const float* __restrict__ sc, const float* __restrict__ bi, u16* __restrict__ xb){
  __shared__ float s4[4];
  int tok = blockIdx.x;
  int t = threadIdx.x;
  float v[3];
  #pragma unroll
  for(int j=0;j<3;j++){
    int i = t + j*256;
    v[j] = x[(ll)tok*DM_+i] + add[(ll)tok*DM_+i];
  }
  float mean = bsum256(v[0]+v[1]+v[2], s4) * (1.0f/DM_);
  float d0=v[0]-mean, d1=v[1]-mean, d2=v[2]-mean;
  float var = bsum256(d0*d0+d1*d1+d2*d2, s4) * (1.0f/DM_);
  float r = rsqrtf(var + 1e-5f);
  #pragma unroll
  for(int j=0;j<3;j++){
    int i = t + j*256;
    float o = (v[j]-mean)*r*sc[i] + bi[i];
    x[(ll)tok*DM_+i] = o;
    xb[(ll)tok*DM_+i] = f2b(o);
  }
}

// ---------------- bf16 MFMA GEMM: C[M,N] = A[M,K] @ Bt[N,K]^T + bias ----------------
template<int MODE>   // 0 = bf16 out, 1 = f32 out, 2 = bf16 out + gelu
__global__ __launch_bounds__(256) void k_mm(const u16* __restrict__ A, const u16* __restrict__ Bt,
    const float* __restrict__ bias, void* __restrict__ Cout, int M, int N, int K){
  __shared__ __align__(16) u16 As[128*32];
  __shared__ __align__(16) u16 Bs[128*32];
  int tid = threadIdx.x, wave = tid>>6, lane = tid&63;
  int m0 = blockIdx.y*128, n0 = blockIdx.x*128;
  int wm = (wave>>1)*64, wn = (wave&1)*64;
  ffrag acc[4][4];
  #pragma unroll
  for(int i=0;i<4;i++)
    #pragma unroll
    for(int j=0;j<4;j++) acc[i][j] = (ffrag){0.f,0.f,0.f,0.f};
  int lrow = lane>>2, lseg = (lane&3)*8;
  const u16* Ap0 = A  + (ll)(m0 + wave*32 + lrow)*K + lseg;
  const u16* Bp0 = Bt + (ll)(n0 + wave*32 + lrow)*K + lseg;
  u16* AsW0 = As + (wave*2+0)*512;
  u16* AsW1 = As + (wave*2+1)*512;
  u16* BsW0 = Bs + (wave*2+0)*512;
  u16* BsW1 = Bs + (wave*2+1)*512;
  int lane15 = lane&15, quad = lane>>4;
  const u16* ArA = As + (wm + lane15)*32 + quad*8;
  const u16* BrB = Bs + (wn + lane15)*32 + quad*8;
  for(int k0=0; k0<K; k0+=32){
    __syncthreads();
    gld16(Ap0 + k0,             AsW0);
    gld16(Ap0 + k0 + (ll)16*K,  AsW1);
    gld16(Bp0 + k0,             BsW0);
    gld16(Bp0 + k0 + (ll)16*K,  BsW1);
    __syncthreads();
    bfrag af[4], bf[4];
    #pragma unroll
    for(int i=0;i<4;i++) af[i] = *(const bfrag*)(ArA + i*512);
    #pragma unroll
    for(int i=0;i<4;i++) bf[i] = *(const bfrag*)(BrB + i*512);
    #pragma unroll
    for(int i=0;i<4;i++)
      #pragma unroll
      for(int j=0;j<4;j++)
        acc[i][j] = __builtin_amdgcn_mfma_f32_16x16x32_bf16(af[i], bf[j], acc[i][j], 0, 0, 0);
  }
  #pragma unroll
  for(int mi=0;mi<4;mi++){
    #pragma unroll
    for(int ni=0;ni<4;ni++){
      int col = n0 + wn + ni*16 + lane15;
      float bv = bias[col];
      #pragma unroll
      for(int r=0;r<4;r++){
        int row = m0 + wm + mi*16 + quad*4 + r;
        float c = acc[mi][ni][r] + bv;
        if(MODE==2) c = gelu_f(c);
        if(MODE==1) ((float*)Cout)[(ll)row*N + col] = c;
        else        ((u16*)Cout)[(ll)row*N + col] = f2b(c);
      }
    }
  }
}

// ---------------- qg = x[:,0] @ Wqg + bqg ----------------
__global__ __launch_bounds__(256) void k_qg(const float* __restrict__ x, const u16* __restrict__ Wt,
    const float* __restrict__ bg, float* __restrict__ qg){
  int b = blockIdx.y;
  int nn = blockIdx.x*256 + threadIdx.x;
  __shared__ float xs[DM_];
  int t = threadIdx.x;
  #pragma unroll
  for(int j=0;j<3;j++) xs[t + j*256] = x[(ll)(b*S_)*DM_ + t + j*256];
  __syncthreads();
  const uint4* wr = (const uint4*)(Wt + (ll)nn*DM_);
  float acc = bg[nn];
  #pragma unroll 4
  for(int g=0; g<96; g++){
    float tf[8]; unp8(wr[g], tf);
    #pragma unroll
    for(int e=0;e<8;e++) acc = fmaf(xs[g*8+e], tf[e], acc);
  }
  qg[b*DM_ + nn] = acc;
}

// ---------------- banded attention: swapped-QK^T MFMA flash ----------------
// grid: dim3(S_/QB_, H_, B_); chunks of 32 keys covering [q0-W, q0+QB_+W)
// Sᵀ layout after mfma(K,Q): col=lane15=query(local), row=quad*4+reg=key(in 16-blk)
// softmax state (m,l) is per-lane scalar; key-reduce = 7 fmax + 2 cross-quad shfl.
__global__ __launch_bounds__(256) void k_band(const u16* __restrict__ qb, const u16* __restrict__ kb,
    const u16* __restrict__ vb, const int* __restrict__ am, u16* __restrict__ aout){
  int nq = blockIdx.x, h = blockIdx.y, b = blockIdx.z;
  int q0 = nq*QB_;
  int tid = threadIdx.x;
  int wave = tid>>6, lane = tid&63, lane15 = lane&15, quad = lane>>4;
  int wq = wave*16;
  __shared__ __align__(16) u16 Ks[32*72];       // [key][d], stride 72
  __shared__ __align__(16) u16 Vt[64*40];       // [d][key], stride 40
  __shared__ __align__(16) u16 Ps[4][16*40];    // per-wave Pᵀ as [q][key], stride 40
  __shared__ __align__(16) float cokA[QB_+2*W_];// per-window key mask, staged once
  __shared__ __align__(16) float k0f[64];
  __shared__ __align__(16) float v0f[64];
  const int kbase = q0 - W_;
  const int am0 = am[b*S_];
  // stage mask for the whole window once
  for(int i=tid; i<QB_+2*W_; i+=256){
    int kp = kbase + i;
    cokA[i] = ((kp>=1) && (kp<S_) && (am[b*S_+kp]>0)) ? 0.f : NEG_;
  }
  if(tid < 64){
    k0f[tid] = b2f(kb[(ll)(b*S_)*QS_ + h*64 + tid]);
    v0f[tid] = b2f(vb[(ll)(b*S_)*QS_ + h*64 + tid]);
  }
  bfrag aq[2];   // Q frag: lane15=q, elems d = kc*32 + quad*8 + j
  {
    const u16* qbase = qb + ((ll)(b*S_ + q0 + wq + lane15))*QS_ + h*64 + quad*8;
    aq[0] = *(const bfrag*)(qbase);
    aq[1] = *(const bfrag*)(qbase + 32);
  }
  ffrag ao[4];   // Oᵀ: d = nt*16 + quad*4 + reg, q = lane15
  #pragma unroll
  for(int j=0;j<4;j++) ao[j] = (ffrag){0.f,0.f,0.f,0.f};
  float ms = -INFINITY, ls = 0.f;

  // skip fully out-of-range chunks at sequence edges
  int c_lo = (kbase < 1) ? ((1 - kbase) / 32) : 0;
  if(c_lo < 0) c_lo = 0;
  int c_hi = (S_ - 1 - kbase) / 32 + 1;
  if(c_hi > NCH_) c_hi = NCH_;

  int skey = tid>>3, sseg = tid&7;
  uint4 kreg;
  union { u16 s[8]; uint4 v; } vreg;
  auto FETCH = [&](int c){
    int kp0 = kbase + c*32;
    if(kp0 >= 0 && kp0 + 31 < S_){
      kreg = *(const uint4*)(kb + ((ll)(b*S_ + kp0 + skey))*QS_ + h*64 + sseg*8);
      const u16* vp = vb + ((ll)(b*S_ + kp0 + wave*8))*QS_ + h*64 + lane;
      #pragma unroll
      for(int j=0;j<8;j++) vreg.s[j] = vp[(ll)j*QS_];
    } else {
      int kp = kp0 + skey;
      kreg = make_uint4(0,0,0,0);
      if((unsigned)kp < (unsigned)S_)
        kreg = *(const uint4*)(kb + ((ll)(b*S_+kp))*QS_ + h*64 + sseg*8);
      #pragma unroll
      for(int j=0;j<8;j++){
        int kp2 = kp0 + wave*8 + j;
        vreg.s[j] = ((unsigned)kp2 < (unsigned)S_) ? vb[((ll)(b*S_+kp2))*QS_ + h*64 + lane] : (u16)0;
      }
    }
  };
  FETCH(c_lo);

  #pragma unroll 1
  for(int c=c_lo; c<c_hi; c++){
    __syncthreads();
    *(uint4*)&Ks[skey*72 + sseg*8] = kreg;
    *(uint4*)&Vt[lane*40 + wave*8] = vreg.v;
    __syncthreads();
    if(c+1 < c_hi) FETCH(c+1);       // overlap next-chunk HBM latency with compute
    // swapped QK^T: st0 = keys 0..15, st1 = keys 16..31 (rows), q = lane15 (col)
    ffrag st0 = (ffrag){0.f,0.f,0.f,0.f};
    ffrag st1 = (ffrag){0.f,0.f,0.f,0.f};
    #pragma unroll
    for(int kc=0;kc<2;kc++){
      bfrag k0r = *(const bfrag*)&Ks[(     lane15)*72 + kc*32 + quad*8];
      bfrag k1r = *(const bfrag*)&Ks[(16 + lane15)*72 + kc*32 + quad*8];
      st0 = __builtin_amdgcn_mfma_f32_16x16x32_bf16(k0r, aq[kc], st0, 0, 0, 0);
      st1 = __builtin_amdgcn_mfma_f32_16x16x32_bf16(k1r, aq[kc], st1, 0, 0, 0);
    }
    float4 ck0 = *(const float4*)&cokA[c*32 + quad*4];
    float4 ck1 = *(const float4*)&cokA[c*32 + 16 + quad*4];
    float cka[8] = {ck0.x,ck0.y,ck0.z,ck0.w, ck1.x,ck1.y,ck1.z,ck1.w};
    int qloc = wq + lane15;
    int jg0 = c*32 + quad*4;
    float s[8];
    #pragma unroll
    for(int r=0;r<4;r++){
      s[r]   = ((unsigned)(jg0 + r      - qloc) <= 512u) ? st0[r]*0.125f + cka[r]   : NEG_;
      s[4+r] = ((unsigned)(jg0 + 16 + r - qloc) <= 512u) ? st1[r]*0.125f + cka[4+r] : NEG_;
    }
    float cm = s[0];
    #pragma unroll
    for(int r=1;r<8;r++) cm = fmaxf(cm, s[r]);
    cm = fmaxf(cm, __shfl_xor(cm,16));
    cm = fmaxf(cm, __shfl_xor(cm,32));
    float mn = fmaxf(ms, cm);
    float al = __expf(ms - mn);
    float p[8], rs = 0.f;
    #pragma unroll
    for(int r=0;r<8;r++){ p[r] = __expf(s[r] - mn); rs += p[r]; }
    rs += __shfl_xor(rs,16);
    rs += __shfl_xor(rs,32);
    ls = ls*al + rs;
    ms = mn;
    #pragma unroll
    for(int nt=0;nt<4;nt++)
      #pragma unroll
      for(int r=0;r<4;r++) ao[nt][r] *= al;
    // write Pᵀ rows: lane holds p for q=lane15, keys {quad*4+r} and {16+quad*4+r}
    u16 pw[8];
    #pragma unroll
    for(int r=0;r<8;r++) pw[r] = f2b(p[r]);
    uint2 w0, w1;
    w0.x = (u32)pw[0] | ((u32)pw[1]<<16); w0.y = (u32)pw[2] | ((u32)pw[3]<<16);
    w1.x = (u32)pw[4] | ((u32)pw[5]<<16); w1.y = (u32)pw[6] | ((u32)pw[7]<<16);
    *(uint2*)&Ps[wave][lane15*40 + quad*4]      = w0;
    *(uint2*)&Ps[wave][lane15*40 + 16 + quad*4] = w1;
    // PV: Oᵀ += Vᵀ · Pᵀ  (same-wave LDS RAW — compiler inserts lgkmcnt wait)
    bfrag pf = *(const bfrag*)&Ps[wave][lane15*40 + quad*8];
    #pragma unroll
    for(int nt=0;nt<4;nt++){
      bfrag vf = *(const bfrag*)&Vt[(nt*16+lane15)*40 + quad*8];
      ao[nt] = __builtin_amdgcn_mfma_f32_16x16x32_bf16(vf, pf, ao[nt], 0, 0, 0);
    }
  }
  // global-token key 0: per-lane partial dot over this lane's 16 d's, reduce over quads
  float sgm;
  {
    float4 ka0 = *(const float4*)&k0f[quad*8];
    float4 ka1 = *(const float4*)&k0f[quad*8 + 4];
    float4 kb0 = *(const float4*)&k0f[32 + quad*8];
    float4 kb1 = *(const float4*)&k0f[32 + quad*8 + 4];
    float k0v[16] = {ka0.x,ka0.y,ka0.z,ka0.w, ka1.x,ka1.y,ka1.z,ka1.w,
                     kb0.x,kb0.y,kb0.z,kb0.w, kb1.x,kb1.y,kb1.z,kb1.w};
    float d = 0.f;
    #pragma unroll
    for(int kc=0;kc<2;kc++)
      #pragma unroll
      for(int j=0;j<8;j++)
        d = fmaf(b2f((u16)aq[kc][j]), k0v[kc*8+j], d);
    d += __shfl_xor(d,16);
    d += __shfl_xor(d,32);
    sgm = d*0.125f + ((am0>0) ? 0.f : NEG_);
  }
  float mn = fmaxf(ms, sgm);
  float al = __expf(ms - mn);
  float pg = __expf(sgm - mn);
  float inv = 1.f / (ls*al + pg);
  u16* obase = aout + ((ll)(b*S_ + q0 + wq + lane15))*DM_ + h*64;
  #pragma unroll
  for(int nt=0;nt<4;nt++){
    float4 v0q = *(const float4*)&v0f[nt*16 + quad*4];
    float v0a[4] = {v0q.x, v0q.y, v0q.z, v0q.w};
    u16 o[4];
    #pragma unroll
    for(int r=0;r<4;r++) o[r] = f2b((ao[nt][r]*al + pg*v0a[r]) * inv);
    uint2 w;
    w.x = (u32)o[0] | ((u32)o[1]<<16);
    w.y = (u32)o[2] | ((u32)o[3]<<16);
    *(uint2*)&obase[nt*16 + quad*4] = w;
  }
}

// ---------------- global-token attention, stage 1: per-chunk partials ----------------
// part[b][h][chunk] = { m_c, l_c, o_c[64] }  (66 floats)
__global__ __launch_bounds__(256) void k_gattn1(const float* __restrict__ qg, const u16* __restrict__ kg,
    const u16* __restrict__ vg, const int* __restrict__ am, float* __restrict__ part){
  int ck = blockIdx.x, h = blockIdx.y, b = blockIdx.z;
  int t = threadIdx.x;
  __shared__ float s4[4];
  __shared__ float qgs[64];
  __shared__ float ps[256];
  __shared__ float obuf[4][64];
  if(t < 64) qgs[t] = qg[b*DM_ + h*64 + t];
  __syncthreads();
  int s = ck*256 + t;
  const uint4* kr = (const uint4*)(kg + (ll)(b*S_+s)*QS_ + h*64);
  float d = 0.f;
  #pragma unroll
  for(int g=0; g<8; g++){
    float tf[8]; unp8(kr[g], tf);
    #pragma unroll
    for(int e=0;e<8;e++) d = fmaf(qgs[g*8+e], tf[e], d);
  }
  float sc = (am[b*S_+s] > 0) ? d*0.125f : NEG_;
  float m_c = bmax256(sc, s4);
  float p = __expf(sc - m_c);
  float l_c = bsum256(p, s4);
  ps[t] = p;
  __syncthreads();
  // o_c[d] = sum_t p_t * v[t][d]; thread (grp,dd) covers 64 positions of group grp
  int dd = t & 63, grp = t >> 6;
  float acc = 0.f;
  const u16* vbase = vg + (ll)(b*S_ + ck*256 + grp*64)*QS_ + h*64 + dd;
  #pragma unroll 8
  for(int j=0;j<64;j++)
    acc = fmaf(ps[grp*64+j], b2f(vbase[(ll)j*QS_]), acc);
  obuf[grp][dd] = acc;
  __syncthreads();
  if(t < 64){
    float o = obuf[0][t] + obuf[1][t] + obuf[2][t] + obuf[3][t];
    float* pp = part + ((ll)(b*H_+h)*GC_ + ck)*66;
    if(t == 0){ pp[0] = m_c; pp[1] = l_c; }
    pp[2+t] = o;
  }
}

// ---------------- global-token attention, stage 2: combine chunks -> aout row 0 ----------------
__global__ void k_gattn2(const float* __restrict__ part, u16* __restrict__ aout){
  int h = blockIdx.x, b = blockIdx.y;
  int t = threadIdx.x;   // 64 threads
  const float* pp = part + ((ll)(b*H_+h)*GC_)*66;
  float m = -INFINITY;
  #pragma unroll
  for(int c=0;c<GC_;c++) m = fmaxf(m, pp[c*66]);
  float l = 0.f, o = 0.f;
  #pragma unroll
  for(int c=0;c<GC_;c++){
    float w = __expf(pp[c*66] - m);
    l += pp[c*66+1]*w;
    o += pp[c*66+2+t]*w;
  }
  aout[(ll)(b*S_)*DM_ + h*64 + t] = f2b(o/l);
}

// ---------------- classifier ----------------
__global__ __launch_bounds__(256) void k_cls(const float* __restrict__ x, const float* __restrict__ Wc,
    const float* __restrict__ bc, void* out, const int* flag){
  __shared__ float s4[4];
  int t = threadIdx.x;
  float a00=0,a01=0,a10=0,a11=0;
  for(int k=t;k<DM_;k+=256){
    float w0 = Wc[k*2], w1 = Wc[k*2+1];
    float x0 = x[k];
    float x1 = x[(ll)S_*DM_ + k];
    a00 = fmaf(x0,w0,a00); a01 = fmaf(x0,w1,a01);
    a10 = fmaf(x1,w0,a10); a11 = fmaf(x1,w1,a11);
  }
  float r00 = bsum256(a00,s4);
  float r01 = bsum256(a01,s4);
  float r10 = bsum256(a10,s4);
  float r11 = bsum256(a11,s4);
  if(t==0){
    float o[4] = {r00+bc[0], r01+bc[1], r10+bc[0], r11+bc[1]};
    if(*flag){
      __hip_bfloat16* ob = (__hip_bfloat16*)out;
      for(int i=0;i<4;i++) ob[i] = __float2bfloat16(o[i]);
    } else {
      float* of = (float*)out;
      for(int i=0;i<4;i++) of[i] = o[i];
    }
  }
}

extern "C" void kernel_launch(void* const* d_in, const int* in_sizes, int n_in,
                              void* d_out, int out_size, void* d_ws, size_t ws_size,
                              hipStream_t stream){
  char* wsb = (char*)d_ws;
  size_t off = 0;
  auto alloc = [&](size_t bytes)->size_t{ off = (off + 255) & ~(size_t)255; size_t r = off; off += bytes; return r; };
  const size_t TOK = (size_t)B_*S_;
  size_t P_flag = alloc(16);
  size_t P_pos  = alloc((size_t)S_*DM_*4);
  size_t P_les  = alloc(DM_*4), P_leb = alloc(DM_*4);
  size_t P_bqkv = alloc((size_t)L_*QS_*4);
  size_t P_bqg  = alloc((size_t)L_*DM_*4);
  size_t P_bo   = alloc((size_t)L_*DM_*4);
  size_t P_b1   = alloc((size_t)L_*DFF_*4);
  size_t P_b2   = alloc((size_t)L_*DM_*4);
  size_t P_l1s  = alloc((size_t)L_*DM_*4), P_l1b = alloc((size_t)L_*DM_*4);
  size_t P_l2s  = alloc((size_t)L_*DM_*4), P_l2b = alloc((size_t)L_*DM_*4);
  size_t P_Wc   = alloc(DM_*2*4), P_bc = alloc(64);
  size_t P_qgb  = alloc((size_t)B_*DM_*4);
  size_t P_part = alloc((size_t)B_*H_*GC_*66*4);
  size_t P_Wqkvt= alloc((size_t)L_*QS_*DM_*2);
  size_t P_Wqgt = alloc((size_t)L_*DM_*DM_*2);
  size_t P_Wot  = alloc((size_t)L_*DM_*DM_*2);
  size_t P_W1t  = alloc((size_t)L_*DM_*DFF_*2);
  size_t P_W2t  = alloc((size_t)L_*DFF_*DM_*2);
  size_t P_x    = alloc(TOK*DM_*4);
  size_t P_tmp  = alloc(TOK*DM_*4);
  size_t P_xb   = alloc(TOK*DM_*2);
  size_t P_qkv  = alloc(TOK*QS_*2);
  size_t P_aout = alloc(TOK*DM_*2);
  size_t P_h    = alloc(TOK*DFF_*2);

  int* flag = (int*)(wsb + P_flag);
  #define FP(o) ((float*)(wsb + (o)))
  #define HP(o) ((u16*)(wsb + (o)))

  k_detect<<<1,1,0,stream>>>(d_in[4], flag);

  k_cvt<<<2048,256,0,stream>>>(d_in[3], 0, FP(P_pos), S_*DM_, flag);

  {
    CvtArgs ca{};
    int ns = 0;
    auto addcv = [&](int idx, size_t dstoff, int soff, int nelem){
      ca.src[ns] = d_in[idx]; ca.dst[ns] = FP(dstoff); ca.soff[ns] = soff; ca.n[ns] = nelem; ns++;
    };
    addcv(4, P_les, 0, DM_); addcv(5, P_leb, 0, DM_);
    addcv(28, P_Wc, 0, DM_*2); addcv(29, P_bc, 0, 2);
    const int bidx[5] = {7,9,11,15,17};
    for(int l=0;l<L_;l++){
      for(int s=0;s<5;s++) addcv(bidx[s], P_bqkv + ((size_t)l*QS_ + s*DM_)*4, l*DM_, DM_);
      addcv(13, P_bqg + (size_t)l*DM_*4,  l*DM_,  DM_);
      addcv(19, P_bo  + (size_t)l*DM_*4,  l*DM_,  DM_);
      addcv(23, P_b1  + (size_t)l*DFF_*4, l*DFF_, DFF_);
      addcv(25, P_b2  + (size_t)l*DM_*4,  l*DM_,  DM_);
      addcv(20, P_l1s + (size_t)l*DM_*4,  l*DM_,  DM_);
      addcv(21, P_l1b + (size_t)l*DM_*4,  l*DM_,  DM_);
      addcv(26, P_l2s + (size_t)l*DM_*4,  l*DM_,  DM_);
      addcv(27, P_l2b + (size_t)l*DM_*4,  l*DM_,  DM_);
    }
    for(int s2=ns; s2<32; s2++){ ca.src[s2]=d_in[4]; ca.dst[s2]=FP(P_les); ca.soff[s2]=0; ca.n[s2]=0; }
    k_cvts<<<dim3(12, ns),256,0,stream>>>(ca, flag);
  }

  {
    TwArgs ta{};
    int nt_ = 0;
    const int widx[5] = {6,8,10,14,16};
    for(int l=0;l<L_;l++){
      for(int s=0;s<5;s++){
        ta.src[nt_] = d_in[widx[s]]; ta.soff[nt_] = (ll)l*DM_*DM_;
        ta.dst[nt_] = HP(P_Wqkvt) + (size_t)l*QS_*DM_ + (size_t)s*DM_*DM_; nt_++;
      }
      ta.src[nt_] = d_in[12]; ta.soff[nt_] = (ll)l*DM_*DM_;
      ta.dst[nt_] = HP(P_Wqgt) + (size_t)l*DM_*DM_; nt_++;
      ta.src[nt_] = d_in[18]; ta.soff[nt_] = (ll)l*DM_*DM_;
      ta.dst[nt_] = HP(P_Wot) + (size_t)l*DM_*DM_; nt_++;
    }
    k_tws<<<dim3(24,24,14),256,0,stream>>>(ta, flag);
  }
  for(int l=0;l<L_;l++){
    k_tw<<<dim3(DFF_/32, DM_/32),256,0,stream>>>(d_in[22], (ll)l*DM_*DFF_,
        HP(P_W1t) + (size_t)l*DFF_*DM_, DM_, DFF_, flag);
    k_tw<<<dim3(DM_/32, DFF_/32),256,0,stream>>>(d_in[24], (ll)l*DFF_*DM_,
        HP(P_W2t) + (size_t)l*DM_*DFF_, DFF_, DM_, flag);
  }

  const int* am = (const int*)d_in[1];
  k_embed<<<(int)TOK,256,0,stream>>>((const int*)d_in[0], d_in[2], FP(P_pos), FP(P_les), FP(P_leb),
                                     FP(P_x), HP(P_xb), flag);
  for(int l=0;l<L_;l++){
    const u16* Wqkvt_l = HP(P_Wqkvt) + (size_t)l*QS_*DM_;
    k_mm<0><<<dim3(QS_/128, TOK/128),256,0,stream>>>(HP(P_xb), Wqkvt_l, FP(P_bqkv) + (size_t)l*QS_,
        HP(P_qkv), (int)TOK, QS_, DM_);
    k_qg<<<dim3(3,B_),256,0,stream>>>(FP(P_x), HP(P_Wqgt) + (size_t)l*DM_*DM_, FP(P_bqg) + (size_t)l*DM_, FP(P_qgb));
    k_band<<<dim3(S_/QB_,H_,B_),256,0,stream>>>(HP(P_qkv), HP(P_qkv)+DM_, HP(P_qkv)+2*DM_, am, HP(P_aout));
    k_gattn1<<<dim3(GC_,H_,B_),256,0,stream>>>(FP(P_qgb), HP(P_qkv)+3*DM_, HP(P_qkv)+4*DM_, am, FP(P_part));
    k_gattn2<<<dim3(H_,B_),64,0,stream>>>(FP(P_part), HP(P_aout));
    k_mm<1><<<dim3(DM_/128, TOK/128),256,0,stream>>>(HP(P_aout), HP(P_Wot) + (size_t)l*DM_*DM_,
        FP(P_bo) + (size_t)l*DM_, FP(P_tmp), (int)TOK, DM_, DM_);
    k_rln<<<(int)TOK,256,0,stream>>>(FP(P_x), FP(P_tmp), FP(P_l1s) + (size_t)l*DM_, FP(P_l1b) + (size_t)l*DM_, HP(P_xb));
    k_mm<2><<<dim3(DFF_/128, TOK/128),256,0,stream>>>(HP(P_xb), HP(P_W1t) + (size_t)l*DFF_*DM_,
        FP(P_b1) + (size_t)l*DFF_, HP(P_h), (int)TOK, DFF_, DM_);
    k_mm<1><<<dim3(DM_/128, TOK/128),256,0,stream>>>(HP(P_h), HP(P_W2t) + (size_t)l*DM_*DFF_,
        FP(P_b2) + (size_t)l*DM_, FP(P_tmp), (int)TOK, DM_, DFF_);
    k_rln<<<(int)TOK,256,0,stream>>>(FP(P_x), FP(P_tmp), FP(P_l2s) + (size_t)l*DM_, FP(P_l2b) + (size_t)l*DM_, HP(P_xb));
  }
  k_cls<<<1,256,0,stream>>>(FP(P_x), FP(P_Wc), FP(P_bc), d_out, flag);
}

// Round 4
// 1026.816 us; speedup vs baseline: 1.1781x; 1.0210x over previous
//
#include <hip/hip_runtime.h>
#include <hip/hip_bf16.h>

#define B_   2
#define S_   4096
#define DM_  768
#define H_   12
#define D_   64
#define W_   256
#define NB_  16
#define DFF_ 3072
#define L_   2
#define QS_  3840
#define NEG_ (-1.0e9f)
#define GC_  16    // gattn chunks
#define QB_  64    // band attn queries per block
#define NCH_ 18    // band attn key chunks: (QB_ + 2*W_)/32

typedef long long ll;
typedef unsigned short u16;
typedef unsigned int   u32;

typedef __attribute__((ext_vector_type(8))) short bfrag;
typedef __attribute__((ext_vector_type(4))) float ffrag;
typedef __attribute__((address_space(1))) unsigned gu32;
typedef __attribute__((address_space(3))) unsigned lu32;

// ---------------- helpers ----------------
__device__ __forceinline__ float b2f(u16 u){ union{u32 i; float f;} x; x.i = ((u32)u)<<16; return x.f; }
__device__ __forceinline__ u16 f2b(float f){
  __hip_bfloat16 h = __float2bfloat16(f);
  union{__hip_bfloat16 h; u16 u;} x; x.h = h; return x.u;
}
__device__ __forceinline__ void unp8(uint4 u, float* f){
  union{u32 i; float v;} a;
  a.i = u.x<<16; f[0]=a.v; a.i = u.x&0xffff0000u; f[1]=a.v;
  a.i = u.y<<16; f[2]=a.v; a.i = u.y&0xffff0000u; f[3]=a.v;
  a.i = u.z<<16; f[4]=a.v; a.i = u.z&0xffff0000u; f[5]=a.v;
  a.i = u.w<<16; f[6]=a.v; a.i = u.w&0xffff0000u; f[7]=a.v;
}
__device__ __forceinline__ void gld16(const void* g, void* l){
  __builtin_amdgcn_global_load_lds((gu32*)g, (lu32*)l, 16, 0, 0);
}
__device__ __forceinline__ float bsum256(float v, float* s4){
  #pragma unroll
  for(int o=32;o>0;o>>=1) v += __shfl_down(v,o,64);
  int w = threadIdx.x>>6;
  __syncthreads();
  if((threadIdx.x&63)==0) s4[w]=v;
  __syncthreads();
  return s4[0]+s4[1]+s4[2]+s4[3];
}
__device__ __forceinline__ float bmax256(float v, float* s4){
  #pragma unroll
  for(int o=32;o>0;o>>=1) v = fmaxf(v,__shfl_down(v,o,64));
  int w = threadIdx.x>>6;
  __syncthreads();
  if((threadIdx.x&63)==0) s4[w]=v;
  __syncthreads();
  return fmaxf(fmaxf(s4[0],s4[1]),fmaxf(s4[2],s4[3]));
}
__device__ __forceinline__ float gelu_f(float x){
  return 0.5f*x*(1.0f+tanhf(0.7978845608028654f*(x+0.044715f*x*x*x)));
}

// ---------------- dtype detect: ln_e_s is all-ones ----------------
__global__ void k_detect(const void* les, int* flag){
  unsigned u = *(const unsigned*)les;
  *flag = (u == 0x3F803F80u) ? 1 : 0;
}

// ---------------- convert float input (f32 or bf16) to f32, with src elem offset ----------------
__global__ void k_cvt(const void* __restrict__ src, ll soff, float* __restrict__ dst, int n, const int* flag){
  int f = *flag;
  int i = blockIdx.x*256 + threadIdx.x;
  int st = gridDim.x*256;
  if(f){
    const u16* s = (const u16*)src + soff;
    for(; i<n; i+=st) dst[i] = b2f(s[i]);
  } else {
    const float* s = (const float*)src + soff;
    for(; i<n; i+=st) dst[i] = s[i];
  }
}

// ---------------- batched small converts ----------------
struct CvtArgs { const void* src[32]; float* dst[32]; int soff[32]; int n[32]; };
__global__ void k_cvts(CvtArgs a, const int* __restrict__ flag){
  int seg = blockIdx.y;
  int i = blockIdx.x*256 + threadIdx.x;
  if(i >= a.n[seg]) return;
  int f = *flag;
  float v = f ? b2f(((const u16*)a.src[seg])[a.soff[seg]+i])
              : ((const float*)a.src[seg])[a.soff[seg]+i];
  a.dst[seg][i] = v;
}

// ---------------- weight transpose: src[R][C] (f32/bf16) -> dst[C][R] bf16 ----------------
__global__ __launch_bounds__(256) void k_tw(const void* __restrict__ src, ll soff, u16* __restrict__ dst,
    int R, int C, const int* __restrict__ flag){
  __shared__ float tile[32][33];
  int f = *flag;
  int tx = threadIdx.x & 31, ty = threadIdx.x >> 5;
  int c = blockIdx.x*32 + tx;
  #pragma unroll
  for(int i=0;i<4;i++){
    int r = blockIdx.y*32 + ty + i*8;
    float v;
    if(f) v = b2f(((const u16*)src)[soff + (ll)r*C + c]);
    else  v = ((const float*)src)[soff + (ll)r*C + c];
    tile[ty + i*8][tx] = v;
  }
  __syncthreads();
  #pragma unroll
  for(int i=0;i<4;i++){
    int orow = blockIdx.x*32 + ty + i*8;
    int oc   = blockIdx.y*32 + tx;
    dst[(ll)orow*R + oc] = f2b(tile[tx][ty + i*8]);
  }
}

// batched 768x768 transposes
struct TwArgs { const void* src[14]; ll soff[14]; u16* dst[14]; };
__global__ __launch_bounds__(256) void k_tws(TwArgs a, const int* __restrict__ flag){
  __shared__ float tile[32][33];
  int z = blockIdx.z;
  const void* src = a.src[z]; ll soff = a.soff[z]; u16* dst = a.dst[z];
  int f = *flag;
  int tx = threadIdx.x & 31, ty = threadIdx.x >> 5;
  int c = blockIdx.x*32 + tx;
  #pragma unroll
  for(int i=0;i<4;i++){
    int r = blockIdx.y*32 + ty + i*8;
    float v;
    if(f) v = b2f(((const u16*)src)[soff + (ll)r*DM_ + c]);
    else  v = ((const float*)src)[soff + (ll)r*DM_ + c];
    tile[ty + i*8][tx] = v;
  }
  __syncthreads();
  #pragma unroll
  for(int i=0;i<4;i++){
    int orow = blockIdx.x*32 + ty + i*8;
    int oc   = blockIdx.y*32 + tx;
    dst[(ll)orow*DM_ + oc] = f2b(tile[tx][ty + i*8]);
  }
}

// ---------------- embedding gather + LN -> x (f32) + xb (bf16) ----------------
__global__ __launch_bounds__(256) void k_embed(const int* __restrict__ ids, const void* __restrict__ wemb,
    const float* __restrict__ pos, const float* __restrict__ es, const float* __restrict__ eb,
    float* __restrict__ x, u16* __restrict__ xb, const int* flag){
  __shared__ float s4[4];
  int tok = blockIdx.x;
  int s = tok & (S_-1);
  int t = threadIdx.x;
  int id = ids[tok];
  int f = *flag;
  float v[3];
  #pragma unroll
  for(int j=0;j<3;j++){
    int i = t + j*256;
    float we = f ? b2f(((const u16*)wemb)[(ll)id*DM_ + i])
                 : ((const float*)wemb)[(ll)id*DM_ + i];
    v[j] = we + pos[s*DM_ + i];
  }
  float mean = bsum256(v[0]+v[1]+v[2], s4) * (1.0f/DM_);
  float d0=v[0]-mean, d1=v[1]-mean, d2=v[2]-mean;
  float var = bsum256(d0*d0+d1*d1+d2*d2, s4) * (1.0f/DM_);
  float r = rsqrtf(var + 1e-5f);
  #pragma unroll
  for(int j=0;j<3;j++){
    int i = t + j*256;
    float o = (v[j]-mean)*r*es[i] + eb[i];
    x[(ll)tok*DM_ + i] = o;
    xb[(ll)tok*DM_ + i] = f2b(o);
  }
}

// ---------------- residual add + LN (in-place x) + bf16 copy ----------------
__global__ __launch_bounds__(256) void k_rln(float* __restrict__ x, const float* __restrict__ add,
    const float* __restrict__ sc, const float* __restrict__ bi, u16* __restrict__ xb){
  __shared__ float s4[4];
  int tok = blockIdx.x;
  int t = threadIdx.x;
  float v[3];
  #pragma unroll
  for(int j=0;j<3;j++){
    int i = t + j*256;
    v[j] = x[(ll)tok*DM_+i] + add[(ll)tok*DM_+i];
  }
  float mean = bsum256(v[0]+v[1]+v[2], s4) * (1.0f/DM_);
  float d0=v[0]-mean, d1=v[1]-mean, d2=v[2]-mean;
  float var = bsum256(d0*d0+d1*d1+d2*d2, s4) * (1.0f/DM_);
  float r = rsqrtf(var + 1e-5f);
  #pragma unroll
  for(int j=0;j<3;j++){
    int i = t + j*256;
    float o = (v[j]-mean)*r*sc[i] + bi[i];
    x[(ll)tok*DM_+i] = o;
    xb[(ll)tok*DM_+i] = f2b(o);
  }
}

// ---------------- bf16 MFMA GEMM: C[M,N] = A[M,K] @ Bt[N,K]^T + bias ----------------
// 1D grid (MT*NT blocks, MT=M/128, NT=N/128), all grids divisible by 8.
// XCD-chunked: linear id raw -> xcd=raw%8 owns contiguous virt chunk.
// Within chunk: stripes of 8 M-tiles, nt-major -> per-XCD L2 holds a fixed
// 1.6 MB A-set for the whole chunk and streams B once.
// K-loop: 2-phase double-buffered LDS; STAGE(t+1) issued before compute(t),
// single __syncthreads() per iter drains vmcnt(0) after the MFMAs.
template<int MODE>   // 0 = bf16 out, 1 = f32 out, 2 = bf16 out + gelu
__global__ __launch_bounds__(256) void k_mm(const u16* __restrict__ A, const u16* __restrict__ Bt,
    const float* __restrict__ bias, void* __restrict__ Cout, int M, int N, int K){
  __shared__ __align__(16) u16 As[2][128*32];
  __shared__ __align__(16) u16 Bs[2][128*32];
  int tid = threadIdx.x, wave = tid>>6, lane = tid&63;
  int MT = M>>7, NT = N>>7;
  int nwg = MT*NT;
  int raw = blockIdx.x;
  int chunk = nwg>>3;
  int virt = ((chunk<<3)==nwg) ? ((raw&7)*chunk + (raw>>3)) : raw;
  int per_stripe = NT<<3;
  int sstripe = virt / per_stripe;
  int rrem = virt - sstripe*per_stripe;
  int nt = rrem>>3;
  int mt = (sstripe<<3) + (rrem&7);
  int m0 = mt<<7, n0 = nt<<7;
  int wm = (wave>>1)*64, wn = (wave&1)*64;
  ffrag acc[4][4];
  #pragma unroll
  for(int i=0;i<4;i++)
    #pragma unroll
    for(int j=0;j<4;j++) acc[i][j] = (ffrag){0.f,0.f,0.f,0.f};
  int lrow = lane>>2, lseg = (lane&3)*8;
  const u16* Ap0 = A  + (ll)(m0 + wave*32 + lrow)*K + lseg;
  const u16* Bp0 = Bt + (ll)(n0 + wave*32 + lrow)*K + lseg;
  u16* AsB = &As[0][0] + wave*1024;   // wave-uniform stage base (lane*16B appended by HW)
  u16* BsB = &Bs[0][0] + wave*1024;
  int lane15 = lane&15, quad = lane>>4;
  const u16* ArA = &As[0][0] + (wm + lane15)*32 + quad*8;
  const u16* BrB = &Bs[0][0] + (wn + lane15)*32 + quad*8;
  int nt32 = K>>5;
  // prologue: stage tile 0 into buf 0
  gld16(Ap0,             AsB);
  gld16(Ap0 + (ll)16*K,  AsB + 512);
  gld16(Bp0,             BsB);
  gld16(Bp0 + (ll)16*K,  BsB + 512);
  __syncthreads();   // drains vmcnt(0) then barriers
  int cur = 0;
  #pragma unroll 1
  for(int t=0; t<nt32; ++t){
    if(t+1 < nt32){
      int k0 = (t+1)<<5;
      int nb = (cur^1)<<12;   // 4096 u16 per buffer
      gld16(Ap0 + k0,            AsB + nb);
      gld16(Ap0 + k0 + (ll)16*K, AsB + nb + 512);
      gld16(Bp0 + k0,            BsB + nb);
      gld16(Bp0 + k0 + (ll)16*K, BsB + nb + 512);
    }
    int cb = cur<<12;
    bfrag af[4], bf[4];
    #pragma unroll
    for(int i=0;i<4;i++) af[i] = *(const bfrag*)(ArA + cb + i*512);
    #pragma unroll
    for(int i=0;i<4;i++) bf[i] = *(const bfrag*)(BrB + cb + i*512);
    #pragma unroll
    for(int i=0;i<4;i++)
      #pragma unroll
      for(int j=0;j<4;j++)
        acc[i][j] = __builtin_amdgcn_mfma_f32_16x16x32_bf16(af[i], bf[j], acc[i][j], 0, 0, 0);
    __syncthreads();   // vmcnt(0) drain: prefetch of t+1 complete; buf swap safe
    cur ^= 1;
  }
  #pragma unroll
  for(int mi=0;mi<4;mi++){
    #pragma unroll
    for(int ni=0;ni<4;ni++){
      int col = n0 + wn + ni*16 + lane15;
      float bv = bias[col];
      #pragma unroll
      for(int r=0;r<4;r++){
        int row = m0 + wm + mi*16 + quad*4 + r;
        float c = acc[mi][ni][r] + bv;
        if(MODE==2) c = gelu_f(c);
        if(MODE==1) ((float*)Cout)[(ll)row*N + col] = c;
        else        ((u16*)Cout)[(ll)row*N + col] = f2b(c);
      }
    }
  }
}

// ---------------- qg = x[:,0] @ Wqg + bqg ----------------
__global__ __launch_bounds__(256) void k_qg(const float* __restrict__ x, const u16* __restrict__ Wt,
    const float* __restrict__ bg, float* __restrict__ qg){
  int b = blockIdx.y;
  int nn = blockIdx.x*256 + threadIdx.x;
  __shared__ float xs[DM_];
  int t = threadIdx.x;
  #pragma unroll
  for(int j=0;j<3;j++) xs[t + j*256] = x[(ll)(b*S_)*DM_ + t + j*256];
  __syncthreads();
  const uint4* wr = (const uint4*)(Wt + (ll)nn*DM_);
  float acc = bg[nn];
  #pragma unroll 4
  for(int g=0; g<96; g++){
    float tf[8]; unp8(wr[g], tf);
    #pragma unroll
    for(int e=0;e<8;e++) acc = fmaf(xs[g*8+e], tf[e], acc);
  }
  qg[b*DM_ + nn] = acc;
}

// ---------------- banded attention: swapped-QK^T MFMA flash ----------------
// grid: dim3(S_/QB_, H_, B_); chunks of 32 keys covering [q0-W, q0+QB_+W)
// Sᵀ layout after mfma(K,Q): col=lane15=query(local), row=quad*4+reg=key(in 16-blk)
// softmax state (m,l) is per-lane scalar; key-reduce = 7 fmax + 2 cross-quad shfl.
__global__ __launch_bounds__(256) void k_band(const u16* __restrict__ qb, const u16* __restrict__ kb,
    const u16* __restrict__ vb, const int* __restrict__ am, u16* __restrict__ aout){
  int nq = blockIdx.x, h = blockIdx.y, b = blockIdx.z;
  int q0 = nq*QB_;
  int tid = threadIdx.x;
  int wave = tid>>6, lane = tid&63, lane15 = lane&15, quad = lane>>4;
  int wq = wave*16;
  __shared__ __align__(16) u16 Ks[32*72];       // [key][d], stride 72
  __shared__ __align__(16) u16 Vt[64*40];       // [d][key], stride 40
  __shared__ __align__(16) u16 Ps[4][16*40];    // per-wave Pᵀ as [q][key], stride 40
  __shared__ __align__(16) float cokA[QB_+2*W_];// per-window key mask, staged once
  __shared__ __align__(16) float k0f[64];
  __shared__ __align__(16) float v0f[64];
  const int kbase = q0 - W_;
  const int am0 = am[b*S_];
  // stage mask for the whole window once
  for(int i=tid; i<QB_+2*W_; i+=256){
    int kp = kbase + i;
    cokA[i] = ((kp>=1) && (kp<S_) && (am[b*S_+kp]>0)) ? 0.f : NEG_;
  }
  if(tid < 64){
    k0f[tid] = b2f(kb[(ll)(b*S_)*QS_ + h*64 + tid]);
    v0f[tid] = b2f(vb[(ll)(b*S_)*QS_ + h*64 + tid]);
  }
  bfrag aq[2];   // Q frag: lane15=q, elems d = kc*32 + quad*8 + j
  {
    const u16* qbase = qb + ((ll)(b*S_ + q0 + wq + lane15))*QS_ + h*64 + quad*8;
    aq[0] = *(const bfrag*)(qbase);
    aq[1] = *(const bfrag*)(qbase + 32);
  }
  ffrag ao[4];   // Oᵀ: d = nt*16 + quad*4 + reg, q = lane15
  #pragma unroll
  for(int j=0;j<4;j++) ao[j] = (ffrag){0.f,0.f,0.f,0.f};
  float ms = -INFINITY, ls = 0.f;

  // skip fully out-of-range chunks at sequence edges
  int c_lo = (kbase < 1) ? ((1 - kbase) / 32) : 0;
  if(c_lo < 0) c_lo = 0;
  int c_hi = (S_ - 1 - kbase) / 32 + 1;
  if(c_hi > NCH_) c_hi = NCH_;

  int skey = tid>>3, sseg = tid&7;
  uint4 kreg;
  union { u16 s[8]; uint4 v; } vreg;
  auto FETCH = [&](int c){
    int kp0 = kbase + c*32;
    if(kp0 >= 0 && kp0 + 31 < S_){
      kreg = *(const uint4*)(kb + ((ll)(b*S_ + kp0 + skey))*QS_ + h*64 + sseg*8);
      const u16* vp = vb + ((ll)(b*S_ + kp0 + wave*8))*QS_ + h*64 + lane;
      #pragma unroll
      for(int j=0;j<8;j++) vreg.s[j] = vp[(ll)j*QS_];
    } else {
      int kp = kp0 + skey;
      kreg = make_uint4(0,0,0,0);
      if((unsigned)kp < (unsigned)S_)
        kreg = *(const uint4*)(kb + ((ll)(b*S_+kp))*QS_ + h*64 + sseg*8);
      #pragma unroll
      for(int j=0;j<8;j++){
        int kp2 = kp0 + wave*8 + j;
        vreg.s[j] = ((unsigned)kp2 < (unsigned)S_) ? vb[((ll)(b*S_+kp2))*QS_ + h*64 + lane] : (u16)0;
      }
    }
  };
  FETCH(c_lo);

  #pragma unroll 1
  for(int c=c_lo; c<c_hi; c++){
    __syncthreads();
    *(uint4*)&Ks[skey*72 + sseg*8] = kreg;
    *(uint4*)&Vt[lane*40 + wave*8] = vreg.v;
    __syncthreads();
    if(c+1 < c_hi) FETCH(c+1);       // overlap next-chunk HBM latency with compute
    // swapped QK^T: st0 = keys 0..15, st1 = keys 16..31 (rows), q = lane15 (col)
    ffrag st0 = (ffrag){0.f,0.f,0.f,0.f};
    ffrag st1 = (ffrag){0.f,0.f,0.f,0.f};
    #pragma unroll
    for(int kc=0;kc<2;kc++){
      bfrag k0r = *(const bfrag*)&Ks[(     lane15)*72 + kc*32 + quad*8];
      bfrag k1r = *(const bfrag*)&Ks[(16 + lane15)*72 + kc*32 + quad*8];
      st0 = __builtin_amdgcn_mfma_f32_16x16x32_bf16(k0r, aq[kc], st0, 0, 0, 0);
      st1 = __builtin_amdgcn_mfma_f32_16x16x32_bf16(k1r, aq[kc], st1, 0, 0, 0);
    }
    float4 ck0 = *(const float4*)&cokA[c*32 + quad*4];
    float4 ck1 = *(const float4*)&cokA[c*32 + 16 + quad*4];
    float cka[8] = {ck0.x,ck0.y,ck0.z,ck0.w, ck1.x,ck1.y,ck1.z,ck1.w};
    int qloc = wq + lane15;
    int jg0 = c*32 + quad*4;
    float s[8];
    #pragma unroll
    for(int r=0;r<4;r++){
      s[r]   = ((unsigned)(jg0 + r      - qloc) <= 512u) ? st0[r]*0.125f + cka[r]   : NEG_;
      s[4+r] = ((unsigned)(jg0 + 16 + r - qloc) <= 512u) ? st1[r]*0.125f + cka[4+r] : NEG_;
    }
    float cm = s[0];
    #pragma unroll
    for(int r=1;r<8;r++) cm = fmaxf(cm, s[r]);
    cm = fmaxf(cm, __shfl_xor(cm,16));
    cm = fmaxf(cm, __shfl_xor(cm,32));
    float mn = fmaxf(ms, cm);
    float al = __expf(ms - mn);
    float p[8], rs = 0.f;
    #pragma unroll
    for(int r=0;r<8;r++){ p[r] = __expf(s[r] - mn); rs += p[r]; }
    rs += __shfl_xor(rs,16);
    rs += __shfl_xor(rs,32);
    ls = ls*al + rs;
    ms = mn;
    #pragma unroll
    for(int nt=0;nt<4;nt++)
      #pragma unroll
      for(int r=0;r<4;r++) ao[nt][r] *= al;
    // write Pᵀ rows: lane holds p for q=lane15, keys {quad*4+r} and {16+quad*4+r}
    u16 pw[8];
    #pragma unroll
    for(int r=0;r<8;r++) pw[r] = f2b(p[r]);
    uint2 w0, w1;
    w0.x = (u32)pw[0] | ((u32)pw[1]<<16); w0.y = (u32)pw[2] | ((u32)pw[3]<<16);
    w1.x = (u32)pw[4] | ((u32)pw[5]<<16); w1.y = (u32)pw[6] | ((u32)pw[7]<<16);
    *(uint2*)&Ps[wave][lane15*40 + quad*4]      = w0;
    *(uint2*)&Ps[wave][lane15*40 + 16 + quad*4] = w1;
    // PV: Oᵀ += Vᵀ · Pᵀ  (same-wave LDS RAW — compiler inserts lgkmcnt wait)
    bfrag pf = *(const bfrag*)&Ps[wave][lane15*40 + quad*8];
    #pragma unroll
    for(int nt=0;nt<4;nt++){
      bfrag vf = *(const bfrag*)&Vt[(nt*16+lane15)*40 + quad*8];
      ao[nt] = __builtin_amdgcn_mfma_f32_16x16x32_bf16(vf, pf, ao[nt], 0, 0, 0);
    }
  }
  // global-token key 0: per-lane partial dot over this lane's 16 d's, reduce over quads
  float sgm;
  {
    float4 ka0 = *(const float4*)&k0f[quad*8];
    float4 ka1 = *(const float4*)&k0f[quad*8 + 4];
    float4 kb0 = *(const float4*)&k0f[32 + quad*8];
    float4 kb1 = *(const float4*)&k0f[32 + quad*8 + 4];
    float k0v[16] = {ka0.x,ka0.y,ka0.z,ka0.w, ka1.x,ka1.y,ka1.z,ka1.w,
                     kb0.x,kb0.y,kb0.z,kb0.w, kb1.x,kb1.y,kb1.z,kb1.w};
    float d = 0.f;
    #pragma unroll
    for(int kc=0;kc<2;kc++)
      #pragma unroll
      for(int j=0;j<8;j++)
        d = fmaf(b2f((u16)aq[kc][j]), k0v[kc*8+j], d);
    d += __shfl_xor(d,16);
    d += __shfl_xor(d,32);
    sgm = d*0.125f + ((am0>0) ? 0.f : NEG_);
  }
  float mn = fmaxf(ms, sgm);
  float al = __expf(ms - mn);
  float pg = __expf(sgm - mn);
  float inv = 1.f / (ls*al + pg);
  u16* obase = aout + ((ll)(b*S_ + q0 + wq + lane15))*DM_ + h*64;
  #pragma unroll
  for(int nt=0;nt<4;nt++){
    float4 v0q = *(const float4*)&v0f[nt*16 + quad*4];
    float v0a[4] = {v0q.x, v0q.y, v0q.z, v0q.w};
    u16 o[4];
    #pragma unroll
    for(int r=0;r<4;r++) o[r] = f2b((ao[nt][r]*al + pg*v0a[r]) * inv);
    uint2 w;
    w.x = (u32)o[0] | ((u32)o[1]<<16);
    w.y = (u32)o[2] | ((u32)o[3]<<16);
    *(uint2*)&obase[nt*16 + quad*4] = w;
  }
}

// ---------------- global-token attention, stage 1: per-chunk partials ----------------
// part[b][h][chunk] = { m_c, l_c, o_c[64] }  (66 floats)
__global__ __launch_bounds__(256) void k_gattn1(const float* __restrict__ qg, const u16* __restrict__ kg,
    const u16* __restrict__ vg, const int* __restrict__ am, float* __restrict__ part){
  int ck = blockIdx.x, h = blockIdx.y, b = blockIdx.z;
  int t = threadIdx.x;
  __shared__ float s4[4];
  __shared__ float qgs[64];
  __shared__ float ps[256];
  __shared__ float obuf[4][64];
  if(t < 64) qgs[t] = qg[b*DM_ + h*64 + t];
  __syncthreads();
  int s = ck*256 + t;
  const uint4* kr = (const uint4*)(kg + (ll)(b*S_+s)*QS_ + h*64);
  float d = 0.f;
  #pragma unroll
  for(int g=0; g<8; g++){
    float tf[8]; unp8(kr[g], tf);
    #pragma unroll
    for(int e=0;e<8;e++) d = fmaf(qgs[g*8+e], tf[e], d);
  }
  float sc = (am[b*S_+s] > 0) ? d*0.125f : NEG_;
  float m_c = bmax256(sc, s4);
  float p = __expf(sc - m_c);
  float l_c = bsum256(p, s4);
  ps[t] = p;
  __syncthreads();
  // o_c[d] = sum_t p_t * v[t][d]; thread (grp,dd) covers 64 positions of group grp
  int dd = t & 63, grp = t >> 6;
  float acc = 0.f;
  const u16* vbase = vg + (ll)(b*S_ + ck*256 + grp*64)*QS_ + h*64 + dd;
  #pragma unroll 8
  for(int j=0;j<64;j++)
    acc = fmaf(ps[grp*64+j], b2f(vbase[(ll)j*QS_]), acc);
  obuf[grp][dd] = acc;
  __syncthreads();
  if(t < 64){
    float o = obuf[0][t] + obuf[1][t] + obuf[2][t] + obuf[3][t];
    float* pp = part + ((ll)(b*H_+h)*GC_ + ck)*66;
    if(t == 0){ pp[0] = m_c; pp[1] = l_c; }
    pp[2+t] = o;
  }
}

// ---------------- global-token attention, stage 2: combine chunks -> aout row 0 ----------------
__global__ void k_gattn2(const float* __restrict__ part, u16* __restrict__ aout){
  int h = blockIdx.x, b = blockIdx.y;
  int t = threadIdx.x;   // 64 threads
  const float* pp = part + ((ll)(b*H_+h)*GC_)*66;
  float m = -INFINITY;
  #pragma unroll
  for(int c=0;c<GC_;c++) m = fmaxf(m, pp[c*66]);
  float l = 0.f, o = 0.f;
  #pragma unroll
  for(int c=0;c<GC_;c++){
    float w = __expf(pp[c*66] - m);
    l += pp[c*66+1]*w;
    o += pp[c*66+2+t]*w;
  }
  aout[(ll)(b*S_)*DM_ + h*64 + t] = f2b(o/l);
}

// ---------------- classifier ----------------
__global__ __launch_bounds__(256) void k_cls(const float* __restrict__ x, const float* __restrict__ Wc,
    const float* __restrict__ bc, void* out, const int* flag){
  __shared__ float s4[4];
  int t = threadIdx.x;
  float a00=0,a01=0,a10=0,a11=0;
  for(int k=t;k<DM_;k+=256){
    float w0 = Wc[k*2], w1 = Wc[k*2+1];
    float x0 = x[k];
    float x1 = x[(ll)S_*DM_ + k];
    a00 = fmaf(x0,w0,a00); a01 = fmaf(x0,w1,a01);
    a10 = fmaf(x1,w0,a10); a11 = fmaf(x1,w1,a11);
  }
  float r00 = bsum256(a00,s4);
  float r01 = bsum256(a01,s4);
  float r10 = bsum256(a10,s4);
  float r11 = bsum256(a11,s4);
  if(t==0){
    float o[4] = {r00+bc[0], r01+bc[1], r10+bc[0], r11+bc[1]};
    if(*flag){
      __hip_bfloat16* ob = (__hip_bfloat16*)out;
      for(int i=0;i<4;i++) ob[i] = __float2bfloat16(o[i]);
    } else {
      float* of = (float*)out;
      for(int i=0;i<4;i++) of[i] = o[i];
    }
  }
}

extern "C" void kernel_launch(void* const* d_in, const int* in_sizes, int n_in,
                              void* d_out, int out_size, void* d_ws, size_t ws_size,
                              hipStream_t stream){
  char* wsb = (char*)d_ws;
  size_t off = 0;
  auto alloc = [&](size_t bytes)->size_t{ off = (off + 255) & ~(size_t)255; size_t r = off; off += bytes; return r; };
  const size_t TOK = (size_t)B_*S_;
  size_t P_flag = alloc(16);
  size_t P_pos  = alloc((size_t)S_*DM_*4);
  size_t P_les  = alloc(DM_*4), P_leb = alloc(DM_*4);
  size_t P_bqkv = alloc((size_t)L_*QS_*4);
  size_t P_bqg  = alloc((size_t)L_*DM_*4);
  size_t P_bo   = alloc((size_t)L_*DM_*4);
  size_t P_b1   = alloc((size_t)L_*DFF_*4);
  size_t P_b2   = alloc((size_t)L_*DM_*4);
  size_t P_l1s  = alloc((size_t)L_*DM_*4), P_l1b = alloc((size_t)L_*DM_*4);
  size_t P_l2s  = alloc((size_t)L_*DM_*4), P_l2b = alloc((size_t)L_*DM_*4);
  size_t P_Wc   = alloc(DM_*2*4), P_bc = alloc(64);
  size_t P_qgb  = alloc((size_t)B_*DM_*4);
  size_t P_part = alloc((size_t)B_*H_*GC_*66*4);
  size_t P_Wqkvt= alloc((size_t)L_*QS_*DM_*2);
  size_t P_Wqgt = alloc((size_t)L_*DM_*DM_*2);
  size_t P_Wot  = alloc((size_t)L_*DM_*DM_*2);
  size_t P_W1t  = alloc((size_t)L_*DM_*DFF_*2);
  size_t P_W2t  = alloc((size_t)L_*DFF_*DM_*2);
  size_t P_x    = alloc(TOK*DM_*4);
  size_t P_tmp  = alloc(TOK*DM_*4);
  size_t P_xb   = alloc(TOK*DM_*2);
  size_t P_qkv  = alloc(TOK*QS_*2);
  size_t P_aout = alloc(TOK*DM_*2);
  size_t P_h    = alloc(TOK*DFF_*2);

  int* flag = (int*)(wsb + P_flag);
  #define FP(o) ((float*)(wsb + (o)))
  #define HP(o) ((u16*)(wsb + (o)))

  k_detect<<<1,1,0,stream>>>(d_in[4], flag);

  k_cvt<<<2048,256,0,stream>>>(d_in[3], 0, FP(P_pos), S_*DM_, flag);

  {
    CvtArgs ca{};
    int ns = 0;
    auto addcv = [&](int idx, size_t dstoff, int soff, int nelem){
      ca.src[ns] = d_in[idx]; ca.dst[ns] = FP(dstoff); ca.soff[ns] = soff; ca.n[ns] = nelem; ns++;
    };
    addcv(4, P_les, 0, DM_); addcv(5, P_leb, 0, DM_);
    addcv(28, P_Wc, 0, DM_*2); addcv(29, P_bc, 0, 2);
    const int bidx[5] = {7,9,11,15,17};
    for(int l=0;l<L_;l++){
      for(int s=0;s<5;s++) addcv(bidx[s], P_bqkv + ((size_t)l*QS_ + s*DM_)*4, l*DM_, DM_);
      addcv(13, P_bqg + (size_t)l*DM_*4,  l*DM_,  DM_);
      addcv(19, P_bo  + (size_t)l*DM_*4,  l*DM_,  DM_);
      addcv(23, P_b1  + (size_t)l*DFF_*4, l*DFF_, DFF_);
      addcv(25, P_b2  + (size_t)l*DM_*4,  l*DM_,  DM_);
      addcv(20, P_l1s + (size_t)l*DM_*4,  l*DM_,  DM_);
      addcv(21, P_l1b + (size_t)l*DM_*4,  l*DM_,  DM_);
      addcv(26, P_l2s + (size_t)l*DM_*4,  l*DM_,  DM_);
      addcv(27, P_l2b + (size_t)l*DM_*4,  l*DM_,  DM_);
    }
    for(int s2=ns; s2<32; s2++){ ca.src[s2]=d_in[4]; ca.dst[s2]=FP(P_les); ca.soff[s2]=0; ca.n[s2]=0; }
    k_cvts<<<dim3(12, ns),256,0,stream>>>(ca, flag);
  }

  {
    TwArgs ta{};
    int nt_ = 0;
    const int widx[5] = {6,8,10,14,16};
    for(int l=0;l<L_;l++){
      for(int s=0;s<5;s++){
        ta.src[nt_] = d_in[widx[s]]; ta.soff[nt_] = (ll)l*DM_*DM_;
        ta.dst[nt_] = HP(P_Wqkvt) + (size_t)l*QS_*DM_ + (size_t)s*DM_*DM_; nt_++;
      }
      ta.src[nt_] = d_in[12]; ta.soff[nt_] = (ll)l*DM_*DM_;
      ta.dst[nt_] = HP(P_Wqgt) + (size_t)l*DM_*DM_; nt_++;
      ta.src[nt_] = d_in[18]; ta.soff[nt_] = (ll)l*DM_*DM_;
      ta.dst[nt_] = HP(P_Wot) + (size_t)l*DM_*DM_; nt_++;
    }
    k_tws<<<dim3(24,24,14),256,0,stream>>>(ta, flag);
  }
  for(int l=0;l<L_;l++){
    k_tw<<<dim3(DFF_/32, DM_/32),256,0,stream>>>(d_in[22], (ll)l*DM_*DFF_,
        HP(P_W1t) + (size_t)l*DFF_*DM_, DM_, DFF_, flag);
    k_tw<<<dim3(DM_/32, DFF_/32),256,0,stream>>>(d_in[24], (ll)l*DFF_*DM_,
        HP(P_W2t) + (size_t)l*DM_*DFF_, DFF_, DM_, flag);
  }

  const int* am = (const int*)d_in[1];
  k_embed<<<(int)TOK,256,0,stream>>>((const int*)d_in[0], d_in[2], FP(P_pos), FP(P_les), FP(P_leb),
                                     FP(P_x), HP(P_xb), flag);
  const int GM = (int)TOK/128;   // 64 M-tiles
  for(int l=0;l<L_;l++){
    const u16* Wqkvt_l = HP(P_Wqkvt) + (size_t)l*QS_*DM_;
    k_mm<0><<<(QS_/128)*GM,256,0,stream>>>(HP(P_xb), Wqkvt_l, FP(P_bqkv) + (size_t)l*QS_,
        HP(P_qkv), (int)TOK, QS_, DM_);
    k_qg<<<dim3(3,B_),256,0,stream>>>(FP(P_x), HP(P_Wqgt) + (size_t)l*DM_*DM_, FP(P_bqg) + (size_t)l*DM_, FP(P_qgb));
    k_band<<<dim3(S_/QB_,H_,B_),256,0,stream>>>(HP(P_qkv), HP(P_qkv)+DM_, HP(P_qkv)+2*DM_, am, HP(P_aout));
    k_gattn1<<<dim3(GC_,H_,B_),256,0,stream>>>(FP(P_qgb), HP(P_qkv)+3*DM_, HP(P_qkv)+4*DM_, am, FP(P_part));
    k_gattn2<<<dim3(H_,B_),64,0,stream>>>(FP(P_part), HP(P_aout));
    k_mm<1><<<(DM_/128)*GM,256,0,stream>>>(HP(P_aout), HP(P_Wot) + (size_t)l*DM_*DM_,
        FP(P_bo) + (size_t)l*DM_, FP(P_tmp), (int)TOK, DM_, DM_);
    k_rln<<<(int)TOK,256,0,stream>>>(FP(P_x), FP(P_tmp), FP(P_l1s) + (size_t)l*DM_, FP(P_l1b) + (size_t)l*DM_, HP(P_xb));
    k_mm<2><<<(DFF_/128)*GM,256,0,stream>>>(HP(P_xb), HP(P_W1t) + (size_t)l*DFF_*DM_,
        FP(P_b1) + (size_t)l*DFF_, HP(P_h), (int)TOK, DFF_, DM_);
    k_mm<1><<<(DM_/128)*GM,256,0,stream>>>(HP(P_h), HP(P_W2t) + (size_t)l*DM_*DFF_,
        FP(P_b2) + (size_t)l*DM_, FP(P_tmp), (int)TOK, DM_, DFF_);
    k_rln<<<(int)TOK,256,0,stream>>>(FP(P_x), FP(P_tmp), FP(P_l2s) + (size_t)l*DM_, FP(P_l2b) + (size_t)l*DM_, HP(P_xb));
  }
  k_cls<<<1,256,0,stream>>>(FP(P_x), FP(P_Wc), FP(P_bc), d_out, flag);
}

// Round 5
// 993.620 us; speedup vs baseline: 1.2175x; 1.0334x over previous
//
#include <hip/hip_runtime.h>
#include <hip/hip_bf16.h>

#define B_   2
#define S_   4096
#define DM_  768
#define H_   12
#define D_   64
#define W_   256
#define NB_  16
#define DFF_ 3072
#define L_   2
#define QS_  3840
#define NEG_ (-1.0e9f)
#define GC_  16    // gattn chunks
#define QB_  64    // band attn queries per block
#define NCH_ 18    // band attn key chunks: (QB_ + 2*W_)/32

typedef long long ll;
typedef unsigned short u16;
typedef unsigned int   u32;

typedef __attribute__((ext_vector_type(8))) short bfrag;
typedef __attribute__((ext_vector_type(4))) float ffrag;
typedef __attribute__((address_space(1))) unsigned gu32;
typedef __attribute__((address_space(3))) unsigned lu32;

// ---------------- helpers ----------------
__device__ __forceinline__ float b2f(u16 u){ union{u32 i; float f;} x; x.i = ((u32)u)<<16; return x.f; }
__device__ __forceinline__ u16 f2b(float f){
  __hip_bfloat16 h = __float2bfloat16(f);
  union{__hip_bfloat16 h; u16 u;} x; x.h = h; return x.u;
}
__device__ __forceinline__ void unp8(uint4 u, float* f){
  union{u32 i; float v;} a;
  a.i = u.x<<16; f[0]=a.v; a.i = u.x&0xffff0000u; f[1]=a.v;
  a.i = u.y<<16; f[2]=a.v; a.i = u.y&0xffff0000u; f[3]=a.v;
  a.i = u.z<<16; f[4]=a.v; a.i = u.z&0xffff0000u; f[5]=a.v;
  a.i = u.w<<16; f[6]=a.v; a.i = u.w&0xffff0000u; f[7]=a.v;
}
__device__ __forceinline__ void gld16(const void* g, void* l){
  __builtin_amdgcn_global_load_lds((gu32*)g, (lu32*)l, 16, 0, 0);
}
__device__ __forceinline__ float bsum256(float v, float* s4){
  #pragma unroll
  for(int o=32;o>0;o>>=1) v += __shfl_down(v,o,64);
  int w = threadIdx.x>>6;
  __syncthreads();
  if((threadIdx.x&63)==0) s4[w]=v;
  __syncthreads();
  return s4[0]+s4[1]+s4[2]+s4[3];
}
__device__ __forceinline__ float bmax256(float v, float* s4){
  #pragma unroll
  for(int o=32;o>0;o>>=1) v = fmaxf(v,__shfl_down(v,o,64));
  int w = threadIdx.x>>6;
  __syncthreads();
  if((threadIdx.x&63)==0) s4[w]=v;
  __syncthreads();
  return fmaxf(fmaxf(s4[0],s4[1]),fmaxf(s4[2],s4[3]));
}
__device__ __forceinline__ float gelu_f(float x){
  return 0.5f*x*(1.0f+tanhf(0.7978845608028654f*(x+0.044715f*x*x*x)));
}

// ---------------- dtype detect: ln_e_s is all-ones ----------------
__global__ void k_detect(const void* les, int* flag){
  unsigned u = *(const unsigned*)les;
  *flag = (u == 0x3F803F80u) ? 1 : 0;
}

// ---------------- convert float input (f32 or bf16) to f32, with src elem offset ----------------
__global__ void k_cvt(const void* __restrict__ src, ll soff, float* __restrict__ dst, int n, const int* flag){
  int f = *flag;
  int i = blockIdx.x*256 + threadIdx.x;
  int st = gridDim.x*256;
  if(f){
    const u16* s = (const u16*)src + soff;
    for(; i<n; i+=st) dst[i] = b2f(s[i]);
  } else {
    const float* s = (const float*)src + soff;
    for(; i<n; i+=st) dst[i] = s[i];
  }
}

// ---------------- batched small converts ----------------
struct CvtArgs { const void* src[32]; float* dst[32]; int soff[32]; int n[32]; };
__global__ void k_cvts(CvtArgs a, const int* __restrict__ flag){
  int seg = blockIdx.y;
  int i = blockIdx.x*256 + threadIdx.x;
  if(i >= a.n[seg]) return;
  int f = *flag;
  float v = f ? b2f(((const u16*)a.src[seg])[a.soff[seg]+i])
              : ((const float*)a.src[seg])[a.soff[seg]+i];
  a.dst[seg][i] = v;
}

// ---------------- weight transpose: src[R][C] (f32/bf16) -> dst[C][R] bf16 ----------------
__global__ __launch_bounds__(256) void k_tw(const void* __restrict__ src, ll soff, u16* __restrict__ dst,
    int R, int C, const int* __restrict__ flag){
  __shared__ float tile[32][33];
  int f = *flag;
  int tx = threadIdx.x & 31, ty = threadIdx.x >> 5;
  int c = blockIdx.x*32 + tx;
  #pragma unroll
  for(int i=0;i<4;i++){
    int r = blockIdx.y*32 + ty + i*8;
    float v;
    if(f) v = b2f(((const u16*)src)[soff + (ll)r*C + c]);
    else  v = ((const float*)src)[soff + (ll)r*C + c];
    tile[ty + i*8][tx] = v;
  }
  __syncthreads();
  #pragma unroll
  for(int i=0;i<4;i++){
    int orow = blockIdx.x*32 + ty + i*8;
    int oc   = blockIdx.y*32 + tx;
    dst[(ll)orow*R + oc] = f2b(tile[tx][ty + i*8]);
  }
}

// batched 768x768 transposes
struct TwArgs { const void* src[14]; ll soff[14]; u16* dst[14]; };
__global__ __launch_bounds__(256) void k_tws(TwArgs a, const int* __restrict__ flag){
  __shared__ float tile[32][33];
  int z = blockIdx.z;
  const void* src = a.src[z]; ll soff = a.soff[z]; u16* dst = a.dst[z];
  int f = *flag;
  int tx = threadIdx.x & 31, ty = threadIdx.x >> 5;
  int c = blockIdx.x*32 + tx;
  #pragma unroll
  for(int i=0;i<4;i++){
    int r = blockIdx.y*32 + ty + i*8;
    float v;
    if(f) v = b2f(((const u16*)src)[soff + (ll)r*DM_ + c]);
    else  v = ((const float*)src)[soff + (ll)r*DM_ + c];
    tile[ty + i*8][tx] = v;
  }
  __syncthreads();
  #pragma unroll
  for(int i=0;i<4;i++){
    int orow = blockIdx.x*32 + ty + i*8;
    int oc   = blockIdx.y*32 + tx;
    dst[(ll)orow*DM_ + oc] = f2b(tile[tx][ty + i*8]);
  }
}

// ---------------- embedding gather + LN -> x (f32) + xb (bf16) ----------------
__global__ __launch_bounds__(256) void k_embed(const int* __restrict__ ids, const void* __restrict__ wemb,
    const float* __restrict__ pos, const float* __restrict__ es, const float* __restrict__ eb,
    float* __restrict__ x, u16* __restrict__ xb, const int* flag){
  __shared__ float s4[4];
  int tok = blockIdx.x;
  int s = tok & (S_-1);
  int t = threadIdx.x;
  int id = ids[tok];
  int f = *flag;
  float v[3];
  #pragma unroll
  for(int j=0;j<3;j++){
    int i = t + j*256;
    float we = f ? b2f(((const u16*)wemb)[(ll)id*DM_ + i])
                 : ((const float*)wemb)[(ll)id*DM_ + i];
    v[j] = we + pos[s*DM_ + i];
  }
  float mean = bsum256(v[0]+v[1]+v[2], s4) * (1.0f/DM_);
  float d0=v[0]-mean, d1=v[1]-mean, d2=v[2]-mean;
  float var = bsum256(d0*d0+d1*d1+d2*d2, s4) * (1.0f/DM_);
  float r = rsqrtf(var + 1e-5f);
  #pragma unroll
  for(int j=0;j<3;j++){
    int i = t + j*256;
    float o = (v[j]-mean)*r*es[i] + eb[i];
    x[(ll)tok*DM_ + i] = o;
    xb[(ll)tok*DM_ + i] = f2b(o);
  }
}

// ---------------- residual add + LN (in-place x) + bf16 copy ----------------
__global__ __launch_bounds__(256) void k_rln(float* __restrict__ x, const float* __restrict__ add,
    const float* __restrict__ sc, const float* __restrict__ bi, u16* __restrict__ xb){
  __shared__ float s4[4];
  int tok = blockIdx.x;
  int t = threadIdx.x;
  float v[3];
  #pragma unroll
  for(int j=0;j<3;j++){
    int i = t + j*256;
    v[j] = x[(ll)tok*DM_+i] + add[(ll)tok*DM_+i];
  }
  float mean = bsum256(v[0]+v[1]+v[2], s4) * (1.0f/DM_);
  float d0=v[0]-mean, d1=v[1]-mean, d2=v[2]-mean;
  float var = bsum256(d0*d0+d1*d1+d2*d2, s4) * (1.0f/DM_);
  float r = rsqrtf(var + 1e-5f);
  #pragma unroll
  for(int j=0;j<3;j++){
    int i = t + j*256;
    float o = (v[j]-mean)*r*sc[i] + bi[i];
    x[(ll)tok*DM_+i] = o;
    xb[(ll)tok*DM_+i] = f2b(o);
  }
}

// ---------------- bf16 MFMA GEMM: C[M,N] = A[M,K] @ Bt[N,K]^T + bias ----------------
// 1D XCD-chunked grid (see R3 notes). K-loop: double-buffered LDS with
// COUNTED vmcnt (T4/m218): never drain vmcnt(0) in steady state.
//   iter t: ds_read(buf[t&1]); lgkmcnt(0); barrier; stage(t+2 -> buf[t&1]);
//           MFMA; vmcnt(4) [t+1's loads done, t+2's fly]; barrier
// Cross-wave safety: barrier #1 after all waves' lgkmcnt(0) -> frags in regs
// before overwrite; per-wave vmcnt before barrier #2 -> staged data published.
template<int MODE>   // 0 = bf16 out, 1 = f32 out, 2 = bf16 out + gelu
__global__ __launch_bounds__(256) void k_mm(const u16* __restrict__ A, const u16* __restrict__ Bt,
    const float* __restrict__ bias, void* __restrict__ Cout, int M, int N, int K){
  __shared__ __align__(16) u16 As[2][128*32];
  __shared__ __align__(16) u16 Bs[2][128*32];
  int tid = threadIdx.x, wave = tid>>6, lane = tid&63;
  int MT = M>>7, NT = N>>7;
  int nwg = MT*NT;
  int raw = blockIdx.x;
  int chunk = nwg>>3;
  int virt = ((chunk<<3)==nwg) ? ((raw&7)*chunk + (raw>>3)) : raw;
  int per_stripe = NT<<3;
  int sstripe = virt / per_stripe;
  int rrem = virt - sstripe*per_stripe;
  int nt = rrem>>3;
  int mt = (sstripe<<3) + (rrem&7);
  int m0 = mt<<7, n0 = nt<<7;
  int wm = (wave>>1)*64, wn = (wave&1)*64;
  ffrag acc[4][4];
  #pragma unroll
  for(int i=0;i<4;i++)
    #pragma unroll
    for(int j=0;j<4;j++) acc[i][j] = (ffrag){0.f,0.f,0.f,0.f};
  int lrow = lane>>2, lseg = (lane&3)*8;
  const u16* Ap0 = A  + (ll)(m0 + wave*32 + lrow)*K + lseg;
  const u16* Bp0 = Bt + (ll)(n0 + wave*32 + lrow)*K + lseg;
  u16* AsB = &As[0][0] + wave*1024;   // wave-uniform stage base (lane*16B appended by HW)
  u16* BsB = &Bs[0][0] + wave*1024;
  int lane15 = lane&15, quad = lane>>4;
  const u16* ArA = &As[0][0] + (wm + lane15)*32 + quad*8;
  const u16* BrB = &Bs[0][0] + (wn + lane15)*32 + quad*8;
  int nt32 = K>>5;
  auto stage = [&](int t, int bufsel){
    int k0 = t<<5;
    int nb = bufsel<<12;   // 4096 u16 per buffer
    gld16(Ap0 + k0,            AsB + nb);
    gld16(Ap0 + k0 + (ll)16*K, AsB + nb + 512);
    gld16(Bp0 + k0,            BsB + nb);
    gld16(Bp0 + k0 + (ll)16*K, BsB + nb + 512);
  };
  // prologue: stage tiles 0 and 1 (K >= 64 always); wait only tile 0 (4 left flying)
  stage(0, 0);
  stage(1, 1);
  asm volatile("s_waitcnt vmcnt(4)" ::: "memory");
  __builtin_amdgcn_s_barrier();
  #pragma unroll 1
  for(int t=0; t<nt32; ++t){
    int cb = (t&1)<<12;
    bfrag af[4], bf[4];
    #pragma unroll
    for(int i=0;i<4;i++) af[i] = *(const bfrag*)(ArA + cb + i*512);
    #pragma unroll
    for(int i=0;i<4;i++) bf[i] = *(const bfrag*)(BrB + cb + i*512);
    asm volatile("s_waitcnt lgkmcnt(0)" ::: "memory");
    __builtin_amdgcn_sched_barrier(0);     // rule #18: keep consumers below the wait
    __builtin_amdgcn_s_barrier();          // all waves have current frags in regs
    if(t+2 < nt32) stage(t+2, t&1);        // overwrite just-consumed buffer
    #pragma unroll
    for(int i=0;i<4;i++)
      #pragma unroll
      for(int j=0;j<4;j++)
        acc[i][j] = __builtin_amdgcn_mfma_f32_16x16x32_bf16(af[i], bf[j], acc[i][j], 0, 0, 0);
    if(t+2 < nt32){
      asm volatile("s_waitcnt vmcnt(4)" ::: "memory");   // t+1's 4 done; t+2's 4 in flight
    } else if(t+1 < nt32){
      asm volatile("s_waitcnt vmcnt(0)" ::: "memory");   // tail: no t+2 loads to hide behind
    }
    __builtin_amdgcn_s_barrier();          // buf[(t+1)&1] published to all waves
  }
  #pragma unroll
  for(int mi=0;mi<4;mi++){
    #pragma unroll
    for(int ni=0;ni<4;ni++){
      int col = n0 + wn + ni*16 + lane15;
      float bv = bias[col];
      #pragma unroll
      for(int r=0;r<4;r++){
        int row = m0 + wm + mi*16 + quad*4 + r;
        float c = acc[mi][ni][r] + bv;
        if(MODE==2) c = gelu_f(c);
        if(MODE==1) ((float*)Cout)[(ll)row*N + col] = c;
        else        ((u16*)Cout)[(ll)row*N + col] = f2b(c);
      }
    }
  }
}

// ---------------- qg = x[:,0] @ Wqg + bqg ----------------
__global__ __launch_bounds__(256) void k_qg(const float* __restrict__ x, const u16* __restrict__ Wt,
    const float* __restrict__ bg, float* __restrict__ qg){
  int b = blockIdx.y;
  int nn = blockIdx.x*256 + threadIdx.x;
  __shared__ float xs[DM_];
  int t = threadIdx.x;
  #pragma unroll
  for(int j=0;j<3;j++) xs[t + j*256] = x[(ll)(b*S_)*DM_ + t + j*256];
  __syncthreads();
  const uint4* wr = (const uint4*)(Wt + (ll)nn*DM_);
  float acc = bg[nn];
  #pragma unroll 4
  for(int g=0; g<96; g++){
    float tf[8]; unp8(wr[g], tf);
    #pragma unroll
    for(int e=0;e<8;e++) acc = fmaf(xs[g*8+e], tf[e], acc);
  }
  qg[b*DM_ + nn] = acc;
}

// ---------------- banded attention: swapped-QK^T MFMA flash ----------------
// grid: dim3(S_/QB_, H_, B_); chunks of 32 keys covering [q0-W, q0+QB_+W)
// Sᵀ layout after mfma(K,Q): col=lane15=query(local), row=quad*4+reg=key(in 16-blk)
// softmax state (m,l) is per-lane scalar; key-reduce = 7 fmax + 2 cross-quad shfl.
__global__ __launch_bounds__(256) void k_band(const u16* __restrict__ qb, const u16* __restrict__ kb,
    const u16* __restrict__ vb, const int* __restrict__ am, u16* __restrict__ aout){
  int nq = blockIdx.x, h = blockIdx.y, b = blockIdx.z;
  int q0 = nq*QB_;
  int tid = threadIdx.x;
  int wave = tid>>6, lane = tid&63, lane15 = lane&15, quad = lane>>4;
  int wq = wave*16;
  __shared__ __align__(16) u16 Ks[32*72];       // [key][d], stride 72
  __shared__ __align__(16) u16 Vt[64*40];       // [d][key], stride 40
  __shared__ __align__(16) u16 Ps[4][16*40];    // per-wave Pᵀ as [q][key], stride 40
  __shared__ __align__(16) float cokA[QB_+2*W_];// per-window key mask, staged once
  __shared__ __align__(16) float k0f[64];
  __shared__ __align__(16) float v0f[64];
  const int kbase = q0 - W_;
  const int am0 = am[b*S_];
  // stage mask for the whole window once
  for(int i=tid; i<QB_+2*W_; i+=256){
    int kp = kbase + i;
    cokA[i] = ((kp>=1) && (kp<S_) && (am[b*S_+kp]>0)) ? 0.f : NEG_;
  }
  if(tid < 64){
    k0f[tid] = b2f(kb[(ll)(b*S_)*QS_ + h*64 + tid]);
    v0f[tid] = b2f(vb[(ll)(b*S_)*QS_ + h*64 + tid]);
  }
  bfrag aq[2];   // Q frag: lane15=q, elems d = kc*32 + quad*8 + j
  {
    const u16* qbase = qb + ((ll)(b*S_ + q0 + wq + lane15))*QS_ + h*64 + quad*8;
    aq[0] = *(const bfrag*)(qbase);
    aq[1] = *(const bfrag*)(qbase + 32);
  }
  ffrag ao[4];   // Oᵀ: d = nt*16 + quad*4 + reg, q = lane15
  #pragma unroll
  for(int j=0;j<4;j++) ao[j] = (ffrag){0.f,0.f,0.f,0.f};
  float ms = -INFINITY, ls = 0.f;

  // skip fully out-of-range chunks at sequence edges
  int c_lo = (kbase < 1) ? ((1 - kbase) / 32) : 0;
  if(c_lo < 0) c_lo = 0;
  int c_hi = (S_ - 1 - kbase) / 32 + 1;
  if(c_hi > NCH_) c_hi = NCH_;

  int skey = tid>>3, sseg = tid&7;
  uint4 kreg;
  union { u16 s[8]; uint4 v; } vreg;
  auto FETCH = [&](int c){
    int kp0 = kbase + c*32;
    if(kp0 >= 0 && kp0 + 31 < S_){
      kreg = *(const uint4*)(kb + ((ll)(b*S_ + kp0 + skey))*QS_ + h*64 + sseg*8);
      const u16* vp = vb + ((ll)(b*S_ + kp0 + wave*8))*QS_ + h*64 + lane;
      #pragma unroll
      for(int j=0;j<8;j++) vreg.s[j] = vp[(ll)j*QS_];
    } else {
      int kp = kp0 + skey;
      kreg = make_uint4(0,0,0,0);
      if((unsigned)kp < (unsigned)S_)
        kreg = *(const uint4*)(kb + ((ll)(b*S_+kp))*QS_ + h*64 + sseg*8);
      #pragma unroll
      for(int j=0;j<8;j++){
        int kp2 = kp0 + wave*8 + j;
        vreg.s[j] = ((unsigned)kp2 < (unsigned)S_) ? vb[((ll)(b*S_+kp2))*QS_ + h*64 + lane] : (u16)0;
      }
    }
  };
  FETCH(c_lo);

  #pragma unroll 1
  for(int c=c_lo; c<c_hi; c++){
    __syncthreads();
    *(uint4*)&Ks[skey*72 + sseg*8] = kreg;
    *(uint4*)&Vt[lane*40 + wave*8] = vreg.v;
    __syncthreads();
    if(c+1 < c_hi) FETCH(c+1);       // overlap next-chunk HBM latency with compute
    // swapped QK^T: st0 = keys 0..15, st1 = keys 16..31 (rows), q = lane15 (col)
    ffrag st0 = (ffrag){0.f,0.f,0.f,0.f};
    ffrag st1 = (ffrag){0.f,0.f,0.f,0.f};
    #pragma unroll
    for(int kc=0;kc<2;kc++){
      bfrag k0r = *(const bfrag*)&Ks[(     lane15)*72 + kc*32 + quad*8];
      bfrag k1r = *(const bfrag*)&Ks[(16 + lane15)*72 + kc*32 + quad*8];
      st0 = __builtin_amdgcn_mfma_f32_16x16x32_bf16(k0r, aq[kc], st0, 0, 0, 0);
      st1 = __builtin_amdgcn_mfma_f32_16x16x32_bf16(k1r, aq[kc], st1, 0, 0, 0);
    }
    float4 ck0 = *(const float4*)&cokA[c*32 + quad*4];
    float4 ck1 = *(const float4*)&cokA[c*32 + 16 + quad*4];
    float cka[8] = {ck0.x,ck0.y,ck0.z,ck0.w, ck1.x,ck1.y,ck1.z,ck1.w};
    int qloc = wq + lane15;
    int jg0 = c*32 + quad*4;
    float s[8];
    #pragma unroll
    for(int r=0;r<4;r++){
      s[r]   = ((unsigned)(jg0 + r      - qloc) <= 512u) ? st0[r]*0.125f + cka[r]   : NEG_;
      s[4+r] = ((unsigned)(jg0 + 16 + r - qloc) <= 512u) ? st1[r]*0.125f + cka[4+r] : NEG_;
    }
    float cm = s[0];
    #pragma unroll
    for(int r=1;r<8;r++) cm = fmaxf(cm, s[r]);
    cm = fmaxf(cm, __shfl_xor(cm,16));
    cm = fmaxf(cm, __shfl_xor(cm,32));
    float mn = fmaxf(ms, cm);
    float al = __expf(ms - mn);
    float p[8], rs = 0.f;
    #pragma unroll
    for(int r=0;r<8;r++){ p[r] = __expf(s[r] - mn); rs += p[r]; }
    rs += __shfl_xor(rs,16);
    rs += __shfl_xor(rs,32);
    ls = ls*al + rs;
    ms = mn;
    #pragma unroll
    for(int nt=0;nt<4;nt++)
      #pragma unroll
      for(int r=0;r<4;r++) ao[nt][r] *= al;
    // write Pᵀ rows: lane holds p for q=lane15, keys {quad*4+r} and {16+quad*4+r}
    u16 pw[8];
    #pragma unroll
    for(int r=0;r<8;r++) pw[r] = f2b(p[r]);
    uint2 w0, w1;
    w0.x = (u32)pw[0] | ((u32)pw[1]<<16); w0.y = (u32)pw[2] | ((u32)pw[3]<<16);
    w1.x = (u32)pw[4] | ((u32)pw[5]<<16); w1.y = (u32)pw[6] | ((u32)pw[7]<<16);
    *(uint2*)&Ps[wave][lane15*40 + quad*4]      = w0;
    *(uint2*)&Ps[wave][lane15*40 + 16 + quad*4] = w1;
    // PV: Oᵀ += Vᵀ · Pᵀ  (same-wave LDS RAW — compiler inserts lgkmcnt wait)
    bfrag pf = *(const bfrag*)&Ps[wave][lane15*40 + quad*8];
    #pragma unroll
    for(int nt=0;nt<4;nt++){
      bfrag vf = *(const bfrag*)&Vt[(nt*16+lane15)*40 + quad*8];
      ao[nt] = __builtin_amdgcn_mfma_f32_16x16x32_bf16(vf, pf, ao[nt], 0, 0, 0);
    }
  }
  // global-token key 0: per-lane partial dot over this lane's 16 d's, reduce over quads
  float sgm;
  {
    float4 ka0 = *(const float4*)&k0f[quad*8];
    float4 ka1 = *(const float4*)&k0f[quad*8 + 4];
    float4 kb0 = *(const float4*)&k0f[32 + quad*8];
    float4 kb1 = *(const float4*)&k0f[32 + quad*8 + 4];
    float k0v[16] = {ka0.x,ka0.y,ka0.z,ka0.w, ka1.x,ka1.y,ka1.z,ka1.w,
                     kb0.x,kb0.y,kb0.z,kb0.w, kb1.x,kb1.y,kb1.z,kb1.w};
    float d = 0.f;
    #pragma unroll
    for(int kc=0;kc<2;kc++)
      #pragma unroll
      for(int j=0;j<8;j++)
        d = fmaf(b2f((u16)aq[kc][j]), k0v[kc*8+j], d);
    d += __shfl_xor(d,16);
    d += __shfl_xor(d,32);
    sgm = d*0.125f + ((am0>0) ? 0.f : NEG_);
  }
  float mn = fmaxf(ms, sgm);
  float al = __expf(ms - mn);
  float pg = __expf(sgm - mn);
  float inv = 1.f / (ls*al + pg);
  u16* obase = aout + ((ll)(b*S_ + q0 + wq + lane15))*DM_ + h*64;
  #pragma unroll
  for(int nt=0;nt<4;nt++){
    float4 v0q = *(const float4*)&v0f[nt*16 + quad*4];
    float v0a[4] = {v0q.x, v0q.y, v0q.z, v0q.w};
    u16 o[4];
    #pragma unroll
    for(int r=0;r<4;r++) o[r] = f2b((ao[nt][r]*al + pg*v0a[r]) * inv);
    uint2 w;
    w.x = (u32)o[0] | ((u32)o[1]<<16);
    w.y = (u32)o[2] | ((u32)o[3]<<16);
    *(uint2*)&obase[nt*16 + quad*4] = w;
  }
}

// ---------------- global-token attention, stage 1: per-chunk partials ----------------
// part[b][h][chunk] = { m_c, l_c, o_c[64] }  (66 floats)
__global__ __launch_bounds__(256) void k_gattn1(const float* __restrict__ qg, const u16* __restrict__ kg,
    const u16* __restrict__ vg, const int* __restrict__ am, float* __restrict__ part){
  int ck = blockIdx.x, h = blockIdx.y, b = blockIdx.z;
  int t = threadIdx.x;
  __shared__ float s4[4];
  __shared__ float qgs[64];
  __shared__ float ps[256];
  __shared__ float obuf[4][64];
  if(t < 64) qgs[t] = qg[b*DM_ + h*64 + t];
  __syncthreads();
  int s = ck*256 + t;
  const uint4* kr = (const uint4*)(kg + (ll)(b*S_+s)*QS_ + h*64);
  float d = 0.f;
  #pragma unroll
  for(int g=0; g<8; g++){
    float tf[8]; unp8(kr[g], tf);
    #pragma unroll
    for(int e=0;e<8;e++) d = fmaf(qgs[g*8+e], tf[e], d);
  }
  float sc = (am[b*S_+s] > 0) ? d*0.125f : NEG_;
  float m_c = bmax256(sc, s4);
  float p = __expf(sc - m_c);
  float l_c = bsum256(p, s4);
  ps[t] = p;
  __syncthreads();
  // o_c[d] = sum_t p_t * v[t][d]; thread (grp,dd) covers 64 positions of group grp
  int dd = t & 63, grp = t >> 6;
  float acc = 0.f;
  const u16* vbase = vg + (ll)(b*S_ + ck*256 + grp*64)*QS_ + h*64 + dd;
  #pragma unroll 8
  for(int j=0;j<64;j++)
    acc = fmaf(ps[grp*64+j], b2f(vbase[(ll)j*QS_]), acc);
  obuf[grp][dd] = acc;
  __syncthreads();
  if(t < 64){
    float o = obuf[0][t] + obuf[1][t] + obuf[2][t] + obuf[3][t];
    float* pp = part + ((ll)(b*H_+h)*GC_ + ck)*66;
    if(t == 0){ pp[0] = m_c; pp[1] = l_c; }
    pp[2+t] = o;
  }
}

// ---------------- global-token attention, stage 2: combine chunks -> aout row 0 ----------------
__global__ void k_gattn2(const float* __restrict__ part, u16* __restrict__ aout){
  int h = blockIdx.x, b = blockIdx.y;
  int t = threadIdx.x;   // 64 threads
  const float* pp = part + ((ll)(b*H_+h)*GC_)*66;
  float m = -INFINITY;
  #pragma unroll
  for(int c=0;c<GC_;c++) m = fmaxf(m, pp[c*66]);
  float l = 0.f, o = 0.f;
  #pragma unroll
  for(int c=0;c<GC_;c++){
    float w = __expf(pp[c*66] - m);
    l += pp[c*66+1]*w;
    o += pp[c*66+2+t]*w;
  }
  aout[(ll)(b*S_)*DM_ + h*64 + t] = f2b(o/l);
}

// ---------------- classifier ----------------
__global__ __launch_bounds__(256) void k_cls(const float* __restrict__ x, const float* __restrict__ Wc,
    const float* __restrict__ bc, void* out, const int* flag){
  __shared__ float s4[4];
  int t = threadIdx.x;
  float a00=0,a01=0,a10=0,a11=0;
  for(int k=t;k<DM_;k+=256){
    float w0 = Wc[k*2], w1 = Wc[k*2+1];
    float x0 = x[k];
    float x1 = x[(ll)S_*DM_ + k];
    a00 = fmaf(x0,w0,a00); a01 = fmaf(x0,w1,a01);
    a10 = fmaf(x1,w0,a10); a11 = fmaf(x1,w1,a11);
  }
  float r00 = bsum256(a00,s4);
  float r01 = bsum256(a01,s4);
  float r10 = bsum256(a10,s4);
  float r11 = bsum256(a11,s4);
  if(t==0){
    float o[4] = {r00+bc[0], r01+bc[1], r10+bc[0], r11+bc[1]};
    if(*flag){
      __hip_bfloat16* ob = (__hip_bfloat16*)out;
      for(int i=0;i<4;i++) ob[i] = __float2bfloat16(o[i]);
    } else {
      float* of = (float*)out;
      for(int i=0;i<4;i++) of[i] = o[i];
    }
  }
}

extern "C" void kernel_launch(void* const* d_in, const int* in_sizes, int n_in,
                              void* d_out, int out_size, void* d_ws, size_t ws_size,
                              hipStream_t stream){
  char* wsb = (char*)d_ws;
  size_t off = 0;
  auto alloc = [&](size_t bytes)->size_t{ off = (off + 255) & ~(size_t)255; size_t r = off; off += bytes; return r; };
  const size_t TOK = (size_t)B_*S_;
  size_t P_flag = alloc(16);
  size_t P_pos  = alloc((size_t)S_*DM_*4);
  size_t P_les  = alloc(DM_*4), P_leb = alloc(DM_*4);
  size_t P_bqkv = alloc((size_t)L_*QS_*4);
  size_t P_bqg  = alloc((size_t)L_*DM_*4);
  size_t P_bo   = alloc((size_t)L_*DM_*4);
  size_t P_b1   = alloc((size_t)L_*DFF_*4);
  size_t P_b2   = alloc((size_t)L_*DM_*4);
  size_t P_l1s  = alloc((size_t)L_*DM_*4), P_l1b = alloc((size_t)L_*DM_*4);
  size_t P_l2s  = alloc((size_t)L_*DM_*4), P_l2b = alloc((size_t)L_*DM_*4);
  size_t P_Wc   = alloc(DM_*2*4), P_bc = alloc(64);
  size_t P_qgb  = alloc((size_t)B_*DM_*4);
  size_t P_part = alloc((size_t)B_*H_*GC_*66*4);
  size_t P_Wqkvt= alloc((size_t)L_*QS_*DM_*2);
  size_t P_Wqgt = alloc((size_t)L_*DM_*DM_*2);
  size_t P_Wot  = alloc((size_t)L_*DM_*DM_*2);
  size_t P_W1t  = alloc((size_t)L_*DM_*DFF_*2);
  size_t P_W2t  = alloc((size_t)L_*DFF_*DM_*2);
  size_t P_x    = alloc(TOK*DM_*4);
  size_t P_tmp  = alloc(TOK*DM_*4);
  size_t P_xb   = alloc(TOK*DM_*2);
  size_t P_qkv  = alloc(TOK*QS_*2);
  size_t P_aout = alloc(TOK*DM_*2);
  size_t P_h    = alloc(TOK*DFF_*2);

  int* flag = (int*)(wsb + P_flag);
  #define FP(o) ((float*)(wsb + (o)))
  #define HP(o) ((u16*)(wsb + (o)))

  k_detect<<<1,1,0,stream>>>(d_in[4], flag);

  k_cvt<<<2048,256,0,stream>>>(d_in[3], 0, FP(P_pos), S_*DM_, flag);

  {
    CvtArgs ca{};
    int ns = 0;
    auto addcv = [&](int idx, size_t dstoff, int soff, int nelem){
      ca.src[ns] = d_in[idx]; ca.dst[ns] = FP(dstoff); ca.soff[ns] = soff; ca.n[ns] = nelem; ns++;
    };
    addcv(4, P_les, 0, DM_); addcv(5, P_leb, 0, DM_);
    addcv(28, P_Wc, 0, DM_*2); addcv(29, P_bc, 0, 2);
    const int bidx[5] = {7,9,11,15,17};
    for(int l=0;l<L_;l++){
      for(int s=0;s<5;s++) addcv(bidx[s], P_bqkv + ((size_t)l*QS_ + s*DM_)*4, l*DM_, DM_);
      addcv(13, P_bqg + (size_t)l*DM_*4,  l*DM_,  DM_);
      addcv(19, P_bo  + (size_t)l*DM_*4,  l*DM_,  DM_);
      addcv(23, P_b1  + (size_t)l*DFF_*4, l*DFF_, DFF_);
      addcv(25, P_b2  + (size_t)l*DM_*4,  l*DM_,  DM_);
      addcv(20, P_l1s + (size_t)l*DM_*4,  l*DM_,  DM_);
      addcv(21, P_l1b + (size_t)l*DM_*4,  l*DM_,  DM_);
      addcv(26, P_l2s + (size_t)l*DM_*4,  l*DM_,  DM_);
      addcv(27, P_l2b + (size_t)l*DM_*4,  l*DM_,  DM_);
    }
    for(int s2=ns; s2<32; s2++){ ca.src[s2]=d_in[4]; ca.dst[s2]=FP(P_les); ca.soff[s2]=0; ca.n[s2]=0; }
    k_cvts<<<dim3(12, ns),256,0,stream>>>(ca, flag);
  }

  {
    TwArgs ta{};
    int nt_ = 0;
    const int widx[5] = {6,8,10,14,16};
    for(int l=0;l<L_;l++){
      for(int s=0;s<5;s++){
        ta.src[nt_] = d_in[widx[s]]; ta.soff[nt_] = (ll)l*DM_*DM_;
        ta.dst[nt_] = HP(P_Wqkvt) + (size_t)l*QS_*DM_ + (size_t)s*DM_*DM_; nt_++;
      }
      ta.src[nt_] = d_in[12]; ta.soff[nt_] = (ll)l*DM_*DM_;
      ta.dst[nt_] = HP(P_Wqgt) + (size_t)l*DM_*DM_; nt_++;
      ta.src[nt_] = d_in[18]; ta.soff[nt_] = (ll)l*DM_*DM_;
      ta.dst[nt_] = HP(P_Wot) + (size_t)l*DM_*DM_; nt_++;
    }
    k_tws<<<dim3(24,24,14),256,0,stream>>>(ta, flag);
  }
  for(int l=0;l<L_;l++){
    k_tw<<<dim3(DFF_/32, DM_/32),256,0,stream>>>(d_in[22], (ll)l*DM_*DFF_,
        HP(P_W1t) + (size_t)l*DFF_*DM_, DM_, DFF_, flag);
    k_tw<<<dim3(DM_/32, DFF_/32),256,0,stream>>>(d_in[24], (ll)l*DFF_*DM_,
        HP(P_W2t) + (size_t)l*DM_*DFF_, DFF_, DM_, flag);
  }

  const int* am = (const int*)d_in[1];
  k_embed<<<(int)TOK,256,0,stream>>>((const int*)d_in[0], d_in[2], FP(P_pos), FP(P_les), FP(P_leb),
                                     FP(P_x), HP(P_xb), flag);
  const int GM = (int)TOK/128;   // 64 M-tiles
  for(int l=0;l<L_;l++){
    const u16* Wqkvt_l = HP(P_Wqkvt) + (size_t)l*QS_*DM_;
    k_mm<0><<<(QS_/128)*GM,256,0,stream>>>(HP(P_xb), Wqkvt_l, FP(P_bqkv) + (size_t)l*QS_,
        HP(P_qkv), (int)TOK, QS_, DM_);
    k_qg<<<dim3(3,B_),256,0,stream>>>(FP(P_x), HP(P_Wqgt) + (size_t)l*DM_*DM_, FP(P_bqg) + (size_t)l*DM_, FP(P_qgb));
    k_band<<<dim3(S_/QB_,H_,B_),256,0,stream>>>(HP(P_qkv), HP(P_qkv)+DM_, HP(P_qkv)+2*DM_, am, HP(P_aout));
    k_gattn1<<<dim3(GC_,H_,B_),256,0,stream>>>(FP(P_qgb), HP(P_qkv)+3*DM_, HP(P_qkv)+4*DM_, am, FP(P_part));
    k_gattn2<<<dim3(H_,B_),64,0,stream>>>(FP(P_part), HP(P_aout));
    k_mm<1><<<(DM_/128)*GM,256,0,stream>>>(HP(P_aout), HP(P_Wot) + (size_t)l*DM_*DM_,
        FP(P_bo) + (size_t)l*DM_, FP(P_tmp), (int)TOK, DM_, DM_);
    k_rln<<<(int)TOK,256,0,stream>>>(FP(P_x), FP(P_tmp), FP(P_l1s) + (size_t)l*DM_, FP(P_l1b) + (size_t)l*DM_, HP(P_xb));
    k_mm<2><<<(DFF_/128)*GM,256,0,stream>>>(HP(P_xb), HP(P_W1t) + (size_t)l*DFF_*DM_,
        FP(P_b1) + (size_t)l*DFF_, HP(P_h), (int)TOK, DFF_, DM_);
    k_mm<1><<<(DM_/128)*GM,256,0,stream>>>(HP(P_h), HP(P_W2t) + (size_t)l*DM_*DFF_,
        FP(P_b2) + (size_t)l*DM_, FP(P_tmp), (int)TOK, DM_, DFF_);
    k_rln<<<(int)TOK,256,0,stream>>>(FP(P_x), FP(P_tmp), FP(P_l2s) + (size_t)l*DM_, FP(P_l2b) + (size_t)l*DM_, HP(P_xb));
  }
  k_cls<<<1,256,0,stream>>>(FP(P_x), FP(P_Wc), FP(P_bc), d_out, flag);
}

// Round 6
// 983.237 us; speedup vs baseline: 1.2303x; 1.0106x over previous
//
#include <hip/hip_runtime.h>
#include <hip/hip_bf16.h>

#define B_   2
#define S_   4096
#define DM_  768
#define H_   12
#define D_   64
#define W_   256
#define NB_  16
#define DFF_ 3072
#define L_   2
#define QS_  3840
#define NEG_ (-1.0e9f)
#define GC_  16    // gattn chunks
#define QB_  64    // band attn queries per block
#define NCH_ 18    // band attn key chunks: (QB_ + 2*W_)/32

typedef long long ll;
typedef unsigned short u16;
typedef unsigned int   u32;

typedef __attribute__((ext_vector_type(8))) short bfrag;
typedef __attribute__((ext_vector_type(4))) float ffrag;
typedef __attribute__((address_space(1))) unsigned gu32;
typedef __attribute__((address_space(3))) unsigned lu32;

// ---------------- helpers ----------------
__device__ __forceinline__ float b2f(u16 u){ union{u32 i; float f;} x; x.i = ((u32)u)<<16; return x.f; }
__device__ __forceinline__ u16 f2b(float f){
  __hip_bfloat16 h = __float2bfloat16(f);
  union{__hip_bfloat16 h; u16 u;} x; x.h = h; return x.u;
}
__device__ __forceinline__ void unp8(uint4 u, float* f){
  union{u32 i; float v;} a;
  a.i = u.x<<16; f[0]=a.v; a.i = u.x&0xffff0000u; f[1]=a.v;
  a.i = u.y<<16; f[2]=a.v; a.i = u.y&0xffff0000u; f[3]=a.v;
  a.i = u.z<<16; f[4]=a.v; a.i = u.z&0xffff0000u; f[5]=a.v;
  a.i = u.w<<16; f[6]=a.v; a.i = u.w&0xffff0000u; f[7]=a.v;
}
__device__ __forceinline__ void gld16(const void* g, void* l){
  __builtin_amdgcn_global_load_lds((gu32*)g, (lu32*)l, 16, 0, 0);
}
__device__ __forceinline__ float bsum256(float v, float* s4){
  #pragma unroll
  for(int o=32;o>0;o>>=1) v += __shfl_down(v,o,64);
  int w = threadIdx.x>>6;
  __syncthreads();
  if((threadIdx.x&63)==0) s4[w]=v;
  __syncthreads();
  return s4[0]+s4[1]+s4[2]+s4[3];
}
__device__ __forceinline__ float bmax256(float v, float* s4){
  #pragma unroll
  for(int o=32;o>0;o>>=1) v = fmaxf(v,__shfl_down(v,o,64));
  int w = threadIdx.x>>6;
  __syncthreads();
  if((threadIdx.x&63)==0) s4[w]=v;
  __syncthreads();
  return fmaxf(fmaxf(s4[0],s4[1]),fmaxf(s4[2],s4[3]));
}
__device__ __forceinline__ float gelu_f(float x){
  return 0.5f*x*(1.0f+tanhf(0.7978845608028654f*(x+0.044715f*x*x*x)));
}

// ---------------- dtype detect: ln_e_s is all-ones ----------------
__global__ void k_detect(const void* les, int* flag){
  unsigned u = *(const unsigned*)les;
  *flag = (u == 0x3F803F80u) ? 1 : 0;
}

// ---------------- convert float input (f32 or bf16) to f32, with src elem offset ----------------
__global__ void k_cvt(const void* __restrict__ src, ll soff, float* __restrict__ dst, int n, const int* flag){
  int f = *flag;
  int i = blockIdx.x*256 + threadIdx.x;
  int st = gridDim.x*256;
  if(f){
    const u16* s = (const u16*)src + soff;
    for(; i<n; i+=st) dst[i] = b2f(s[i]);
  } else {
    const float* s = (const float*)src + soff;
    for(; i<n; i+=st) dst[i] = s[i];
  }
}

// ---------------- batched small converts ----------------
struct CvtArgs { const void* src[32]; float* dst[32]; int soff[32]; int n[32]; };
__global__ void k_cvts(CvtArgs a, const int* __restrict__ flag){
  int seg = blockIdx.y;
  int i = blockIdx.x*256 + threadIdx.x;
  if(i >= a.n[seg]) return;
  int f = *flag;
  float v = f ? b2f(((const u16*)a.src[seg])[a.soff[seg]+i])
              : ((const float*)a.src[seg])[a.soff[seg]+i];
  a.dst[seg][i] = v;
}

// ---------------- weight transpose: src[R][C] (f32/bf16) -> dst[C][R] bf16 ----------------
__global__ __launch_bounds__(256) void k_tw(const void* __restrict__ src, ll soff, u16* __restrict__ dst,
    int R, int C, const int* __restrict__ flag){
  __shared__ float tile[32][33];
  int f = *flag;
  int tx = threadIdx.x & 31, ty = threadIdx.x >> 5;
  int c = blockIdx.x*32 + tx;
  #pragma unroll
  for(int i=0;i<4;i++){
    int r = blockIdx.y*32 + ty + i*8;
    float v;
    if(f) v = b2f(((const u16*)src)[soff + (ll)r*C + c]);
    else  v = ((const float*)src)[soff + (ll)r*C + c];
    tile[ty + i*8][tx] = v;
  }
  __syncthreads();
  #pragma unroll
  for(int i=0;i<4;i++){
    int orow = blockIdx.x*32 + ty + i*8;
    int oc   = blockIdx.y*32 + tx;
    dst[(ll)orow*R + oc] = f2b(tile[tx][ty + i*8]);
  }
}

// batched 768x768 transposes
struct TwArgs { const void* src[14]; ll soff[14]; u16* dst[14]; };
__global__ __launch_bounds__(256) void k_tws(TwArgs a, const int* __restrict__ flag){
  __shared__ float tile[32][33];
  int z = blockIdx.z;
  const void* src = a.src[z]; ll soff = a.soff[z]; u16* dst = a.dst[z];
  int f = *flag;
  int tx = threadIdx.x & 31, ty = threadIdx.x >> 5;
  int c = blockIdx.x*32 + tx;
  #pragma unroll
  for(int i=0;i<4;i++){
    int r = blockIdx.y*32 + ty + i*8;
    float v;
    if(f) v = b2f(((const u16*)src)[soff + (ll)r*DM_ + c]);
    else  v = ((const float*)src)[soff + (ll)r*DM_ + c];
    tile[ty + i*8][tx] = v;
  }
  __syncthreads();
  #pragma unroll
  for(int i=0;i<4;i++){
    int orow = blockIdx.x*32 + ty + i*8;
    int oc   = blockIdx.y*32 + tx;
    dst[(ll)orow*DM_ + oc] = f2b(tile[tx][ty + i*8]);
  }
}

// ---------------- embedding gather + LN -> x (f32) + xb (bf16) ----------------
__global__ __launch_bounds__(256) void k_embed(const int* __restrict__ ids, const void* __restrict__ wemb,
    const float* __restrict__ pos, const float* __restrict__ es, const float* __restrict__ eb,
    float* __restrict__ x, u16* __restrict__ xb, const int* flag){
  __shared__ float s4[4];
  int tok = blockIdx.x;
  int s = tok & (S_-1);
  int t = threadIdx.x;
  int id = ids[tok];
  int f = *flag;
  float v[3];
  #pragma unroll
  for(int j=0;j<3;j++){
    int i = t + j*256;
    float we = f ? b2f(((const u16*)wemb)[(ll)id*DM_ + i])
                 : ((const float*)wemb)[(ll)id*DM_ + i];
    v[j] = we + pos[s*DM_ + i];
  }
  float mean = bsum256(v[0]+v[1]+v[2], s4) * (1.0f/DM_);
  float d0=v[0]-mean, d1=v[1]-mean, d2=v[2]-mean;
  float var = bsum256(d0*d0+d1*d1+d2*d2, s4) * (1.0f/DM_);
  float r = rsqrtf(var + 1e-5f);
  #pragma unroll
  for(int j=0;j<3;j++){
    int i = t + j*256;
    float o = (v[j]-mean)*r*es[i] + eb[i];
    x[(ll)tok*DM_ + i] = o;
    xb[(ll)tok*DM_ + i] = f2b(o);
  }
}

// ---------------- residual add + LN (in-place x) + bf16 copy ----------------
__global__ __launch_bounds__(256) void k_rln(float* __restrict__ x, const float* __restrict__ add,
    const float* __restrict__ sc, const float* __restrict__ bi, u16* __restrict__ xb){
  __shared__ float s4[4];
  int tok = blockIdx.x;
  int t = threadIdx.x;
  float v[3];
  #pragma unroll
  for(int j=0;j<3;j++){
    int i = t + j*256;
    v[j] = x[(ll)tok*DM_+i] + add[(ll)tok*DM_+i];
  }
  float mean = bsum256(v[0]+v[1]+v[2], s4) * (1.0f/DM_);
  float d0=v[0]-mean, d1=v[1]-mean, d2=v[2]-mean;
  float var = bsum256(d0*d0+d1*d1+d2*d2, s4) * (1.0f/DM_);
  float r = rsqrtf(var + 1e-5f);
  #pragma unroll
  for(int j=0;j<3;j++){
    int i = t + j*256;
    float o = (v[j]-mean)*r*sc[i] + bi[i];
    x[(ll)tok*DM_+i] = o;
    xb[(ll)tok*DM_+i] = f2b(o);
  }
}

// ---------------- bf16 MFMA GEMM: C[M,N] = A[M,K] @ Bt[N,K]^T + bias ----------------
// 1D XCD-chunked grid; counted-vmcnt double-buffer (T4); T2 chunk-rotation
// swizzle: chunk c of LDS row r stored at position (c + (r>>1))&3 -> b128
// reads hit all 8 bank-slots with 2 lanes each (2-way = free, was 8-way).
// Both-sides rule #21: linear LDS dest (gload_lds), pre-permuted GLOBAL src,
// matching permuted read offset. T5: setprio(1) around MFMA cluster.
template<int MODE>   // 0 = bf16 out, 1 = f32 out, 2 = bf16 out + gelu
__global__ __launch_bounds__(256) void k_mm(const u16* __restrict__ A, const u16* __restrict__ Bt,
    const float* __restrict__ bias, void* __restrict__ Cout, int M, int N, int K){
  __shared__ __align__(16) u16 As[2][128*32];
  __shared__ __align__(16) u16 Bs[2][128*32];
  int tid = threadIdx.x, wave = tid>>6, lane = tid&63;
  int MT = M>>7, NT = N>>7;
  int nwg = MT*NT;
  int raw = blockIdx.x;
  int chunk = nwg>>3;
  int virt = ((chunk<<3)==nwg) ? ((raw&7)*chunk + (raw>>3)) : raw;
  int per_stripe = NT<<3;
  int sstripe = virt / per_stripe;
  int rrem = virt - sstripe*per_stripe;
  int nt = rrem>>3;
  int mt = (sstripe<<3) + (rrem&7);
  int m0 = mt<<7, n0 = nt<<7;
  int wm = (wave>>1)*64, wn = (wave&1)*64;
  ffrag acc[4][4];
  #pragma unroll
  for(int i=0;i<4;i++)
    #pragma unroll
    for(int j=0;j<4;j++) acc[i][j] = (ffrag){0.f,0.f,0.f,0.f};
  int lrow = lane>>2;
  int csrc = ((lane&3) - (lrow>>1)) & 3;   // global chunk that lands at LDS pos lane&3
  int lseg = csrc*8;
  const u16* Ap0 = A  + (ll)(m0 + wave*32 + lrow)*K + lseg;
  const u16* Bp0 = Bt + (ll)(n0 + wave*32 + lrow)*K + lseg;
  u16* AsB = &As[0][0] + wave*1024;   // wave-uniform stage base (lane*16B appended by HW)
  u16* BsB = &Bs[0][0] + wave*1024;
  int lane15 = lane&15, quad = lane>>4;
  int rsw = ((quad + (lane15>>1)) & 3)*8;  // read: chunk quad lives at rotated position
  const u16* ArA = &As[0][0] + (wm + lane15)*32 + rsw;
  const u16* BrB = &Bs[0][0] + (wn + lane15)*32 + rsw;
  int nt32 = K>>5;
  auto stage = [&](int t, int bufsel){
    int k0 = t<<5;
    int nb = bufsel<<12;   // 4096 u16 per buffer
    gld16(Ap0 + k0,            AsB + nb);
    gld16(Ap0 + k0 + (ll)16*K, AsB + nb + 512);
    gld16(Bp0 + k0,            BsB + nb);
    gld16(Bp0 + k0 + (ll)16*K, BsB + nb + 512);
  };
  // prologue: stage tiles 0 and 1 (K >= 64 always); wait only tile 0 (4 left flying)
  stage(0, 0);
  stage(1, 1);
  asm volatile("s_waitcnt vmcnt(4)" ::: "memory");
  __builtin_amdgcn_s_barrier();
  #pragma unroll 1
  for(int t=0; t<nt32; ++t){
    int cb = (t&1)<<12;
    bfrag af[4], bf[4];
    #pragma unroll
    for(int i=0;i<4;i++) af[i] = *(const bfrag*)(ArA + cb + i*512);
    #pragma unroll
    for(int i=0;i<4;i++) bf[i] = *(const bfrag*)(BrB + cb + i*512);
    asm volatile("s_waitcnt lgkmcnt(0)" ::: "memory");
    __builtin_amdgcn_sched_barrier(0);     // rule #18: keep consumers below the wait
    __builtin_amdgcn_s_barrier();          // all waves have current frags in regs
    if(t+2 < nt32) stage(t+2, t&1);        // overwrite just-consumed buffer
    __builtin_amdgcn_s_setprio(1);         // T5: favor MFMA-entering wave
    #pragma unroll
    for(int i=0;i<4;i++)
      #pragma unroll
      for(int j=0;j<4;j++)
        acc[i][j] = __builtin_amdgcn_mfma_f32_16x16x32_bf16(af[i], bf[j], acc[i][j], 0, 0, 0);
    __builtin_amdgcn_s_setprio(0);
    if(t+2 < nt32){
      asm volatile("s_waitcnt vmcnt(4)" ::: "memory");   // t+1's 4 done; t+2's 4 in flight
    } else if(t+1 < nt32){
      asm volatile("s_waitcnt vmcnt(0)" ::: "memory");   // tail: no t+2 loads to hide behind
    }
    __builtin_amdgcn_s_barrier();          // buf[(t+1)&1] published to all waves
  }
  #pragma unroll
  for(int mi=0;mi<4;mi++){
    #pragma unroll
    for(int ni=0;ni<4;ni++){
      int col = n0 + wn + ni*16 + lane15;
      float bv = bias[col];
      #pragma unroll
      for(int r=0;r<4;r++){
        int row = m0 + wm + mi*16 + quad*4 + r;
        float c = acc[mi][ni][r] + bv;
        if(MODE==2) c = gelu_f(c);
        if(MODE==1) ((float*)Cout)[(ll)row*N + col] = c;
        else        ((u16*)Cout)[(ll)row*N + col] = f2b(c);
      }
    }
  }
}

// ---------------- qg = x[:,0] @ Wqg + bqg ----------------
__global__ __launch_bounds__(256) void k_qg(const float* __restrict__ x, const u16* __restrict__ Wt,
    const float* __restrict__ bg, float* __restrict__ qg){
  int b = blockIdx.y;
  int nn = blockIdx.x*256 + threadIdx.x;
  __shared__ float xs[DM_];
  int t = threadIdx.x;
  #pragma unroll
  for(int j=0;j<3;j++) xs[t + j*256] = x[(ll)(b*S_)*DM_ + t + j*256];
  __syncthreads();
  const uint4* wr = (const uint4*)(Wt + (ll)nn*DM_);
  float acc = bg[nn];
  #pragma unroll 4
  for(int g=0; g<96; g++){
    float tf[8]; unp8(wr[g], tf);
    #pragma unroll
    for(int e=0;e<8;e++) acc = fmaf(xs[g*8+e], tf[e], acc);
  }
  qg[b*DM_ + nn] = acc;
}

// ---------------- banded attention: swapped-QK^T MFMA flash ----------------
// grid: dim3(S_/QB_, H_, B_); chunks of 32 keys covering [q0-W, q0+QB_+W)
// Sᵀ layout after mfma(K,Q): col=lane15=query(local), row=quad*4+reg=key(in 16-blk)
// softmax state (m,l) is per-lane scalar; key-reduce = 7 fmax + 2 cross-quad shfl.
__global__ __launch_bounds__(256) void k_band(const u16* __restrict__ qb, const u16* __restrict__ kb,
    const u16* __restrict__ vb, const int* __restrict__ am, u16* __restrict__ aout){
  int nq = blockIdx.x, h = blockIdx.y, b = blockIdx.z;
  int q0 = nq*QB_;
  int tid = threadIdx.x;
  int wave = tid>>6, lane = tid&63, lane15 = lane&15, quad = lane>>4;
  int wq = wave*16;
  __shared__ __align__(16) u16 Ks[32*72];       // [key][d], stride 72
  __shared__ __align__(16) u16 Vt[64*40];       // [d][key], stride 40
  __shared__ __align__(16) u16 Ps[4][16*40];    // per-wave Pᵀ as [q][key], stride 40
  __shared__ __align__(16) float cokA[QB_+2*W_];// per-window key mask, staged once
  __shared__ __align__(16) float k0f[64];
  __shared__ __align__(16) float v0f[64];
  const int kbase = q0 - W_;
  const int am0 = am[b*S_];
  // stage mask for the whole window once
  for(int i=tid; i<QB_+2*W_; i+=256){
    int kp = kbase + i;
    cokA[i] = ((kp>=1) && (kp<S_) && (am[b*S_+kp]>0)) ? 0.f : NEG_;
  }
  if(tid < 64){
    k0f[tid] = b2f(kb[(ll)(b*S_)*QS_ + h*64 + tid]);
    v0f[tid] = b2f(vb[(ll)(b*S_)*QS_ + h*64 + tid]);
  }
  bfrag aq[2];   // Q frag: lane15=q, elems d = kc*32 + quad*8 + j
  {
    const u16* qbase = qb + ((ll)(b*S_ + q0 + wq + lane15))*QS_ + h*64 + quad*8;
    aq[0] = *(const bfrag*)(qbase);
    aq[1] = *(const bfrag*)(qbase + 32);
  }
  ffrag ao[4];   // Oᵀ: d = nt*16 + quad*4 + reg, q = lane15
  #pragma unroll
  for(int j=0;j<4;j++) ao[j] = (ffrag){0.f,0.f,0.f,0.f};
  float ms = -INFINITY, ls = 0.f;

  // skip fully out-of-range chunks at sequence edges
  int c_lo = (kbase < 1) ? ((1 - kbase) / 32) : 0;
  if(c_lo < 0) c_lo = 0;
  int c_hi = (S_ - 1 - kbase) / 32 + 1;
  if(c_hi > NCH_) c_hi = NCH_;

  int skey = tid>>3, sseg = tid&7;
  uint4 kreg;
  union { u16 s[8]; uint4 v; } vreg;
  auto FETCH = [&](int c){
    int kp0 = kbase + c*32;
    if(kp0 >= 0 && kp0 + 31 < S_){
      kreg = *(const uint4*)(kb + ((ll)(b*S_ + kp0 + skey))*QS_ + h*64 + sseg*8);
      const u16* vp = vb + ((ll)(b*S_ + kp0 + wave*8))*QS_ + h*64 + lane;
      #pragma unroll
      for(int j=0;j<8;j++) vreg.s[j] = vp[(ll)j*QS_];
    } else {
      int kp = kp0 + skey;
      kreg = make_uint4(0,0,0,0);
      if((unsigned)kp < (unsigned)S_)
        kreg = *(const uint4*)(kb + ((ll)(b*S_+kp))*QS_ + h*64 + sseg*8);
      #pragma unroll
      for(int j=0;j<8;j++){
        int kp2 = kp0 + wave*8 + j;
        vreg.s[j] = ((unsigned)kp2 < (unsigned)S_) ? vb[((ll)(b*S_+kp2))*QS_ + h*64 + lane] : (u16)0;
      }
    }
  };
  FETCH(c_lo);

  #pragma unroll 1
  for(int c=c_lo; c<c_hi; c++){
    __syncthreads();
    *(uint4*)&Ks[skey*72 + sseg*8] = kreg;
    *(uint4*)&Vt[lane*40 + wave*8] = vreg.v;
    __syncthreads();
    if(c+1 < c_hi) FETCH(c+1);       // overlap next-chunk HBM latency with compute
    // swapped QK^T: st0 = keys 0..15, st1 = keys 16..31 (rows), q = lane15 (col)
    ffrag st0 = (ffrag){0.f,0.f,0.f,0.f};
    ffrag st1 = (ffrag){0.f,0.f,0.f,0.f};
    #pragma unroll
    for(int kc=0;kc<2;kc++){
      bfrag k0r = *(const bfrag*)&Ks[(     lane15)*72 + kc*32 + quad*8];
      bfrag k1r = *(const bfrag*)&Ks[(16 + lane15)*72 + kc*32 + quad*8];
      st0 = __builtin_amdgcn_mfma_f32_16x16x32_bf16(k0r, aq[kc], st0, 0, 0, 0);
      st1 = __builtin_amdgcn_mfma_f32_16x16x32_bf16(k1r, aq[kc], st1, 0, 0, 0);
    }
    float4 ck0 = *(const float4*)&cokA[c*32 + quad*4];
    float4 ck1 = *(const float4*)&cokA[c*32 + 16 + quad*4];
    float cka[8] = {ck0.x,ck0.y,ck0.z,ck0.w, ck1.x,ck1.y,ck1.z,ck1.w};
    int qloc = wq + lane15;
    int jg0 = c*32 + quad*4;
    float s[8];
    #pragma unroll
    for(int r=0;r<4;r++){
      s[r]   = ((unsigned)(jg0 + r      - qloc) <= 512u) ? st0[r]*0.125f + cka[r]   : NEG_;
      s[4+r] = ((unsigned)(jg0 + 16 + r - qloc) <= 512u) ? st1[r]*0.125f + cka[4+r] : NEG_;
    }
    float cm = s[0];
    #pragma unroll
    for(int r=1;r<8;r++) cm = fmaxf(cm, s[r]);
    cm = fmaxf(cm, __shfl_xor(cm,16));
    cm = fmaxf(cm, __shfl_xor(cm,32));
    float mn = fmaxf(ms, cm);
    float al = __expf(ms - mn);
    float p[8], rs = 0.f;
    #pragma unroll
    for(int r=0;r<8;r++){ p[r] = __expf(s[r] - mn); rs += p[r]; }
    rs += __shfl_xor(rs,16);
    rs += __shfl_xor(rs,32);
    ls = ls*al + rs;
    ms = mn;
    #pragma unroll
    for(int nt=0;nt<4;nt++)
      #pragma unroll
      for(int r=0;r<4;r++) ao[nt][r] *= al;
    // write Pᵀ rows: lane holds p for q=lane15, keys {quad*4+r} and {16+quad*4+r}
    u16 pw[8];
    #pragma unroll
    for(int r=0;r<8;r++) pw[r] = f2b(p[r]);
    uint2 w0, w1;
    w0.x = (u32)pw[0] | ((u32)pw[1]<<16); w0.y = (u32)pw[2] | ((u32)pw[3]<<16);
    w1.x = (u32)pw[4] | ((u32)pw[5]<<16); w1.y = (u32)pw[6] | ((u32)pw[7]<<16);
    *(uint2*)&Ps[wave][lane15*40 + quad*4]      = w0;
    *(uint2*)&Ps[wave][lane15*40 + 16 + quad*4] = w1;
    // PV: Oᵀ += Vᵀ · Pᵀ  (same-wave LDS RAW — compiler inserts lgkmcnt wait)
    bfrag pf = *(const bfrag*)&Ps[wave][lane15*40 + quad*8];
    #pragma unroll
    for(int nt=0;nt<4;nt++){
      bfrag vf = *(const bfrag*)&Vt[(nt*16+lane15)*40 + quad*8];
      ao[nt] = __builtin_amdgcn_mfma_f32_16x16x32_bf16(vf, pf, ao[nt], 0, 0, 0);
    }
  }
  // global-token key 0: per-lane partial dot over this lane's 16 d's, reduce over quads
  float sgm;
  {
    float4 ka0 = *(const float4*)&k0f[quad*8];
    float4 ka1 = *(const float4*)&k0f[quad*8 + 4];
    float4 kb0 = *(const float4*)&k0f[32 + quad*8];
    float4 kb1 = *(const float4*)&k0f[32 + quad*8 + 4];
    float k0v[16] = {ka0.x,ka0.y,ka0.z,ka0.w, ka1.x,ka1.y,ka1.z,ka1.w,
                     kb0.x,kb0.y,kb0.z,kb0.w, kb1.x,kb1.y,kb1.z,kb1.w};
    float d = 0.f;
    #pragma unroll
    for(int kc=0;kc<2;kc++)
      #pragma unroll
      for(int j=0;j<8;j++)
        d = fmaf(b2f((u16)aq[kc][j]), k0v[kc*8+j], d);
    d += __shfl_xor(d,16);
    d += __shfl_xor(d,32);
    sgm = d*0.125f + ((am0>0) ? 0.f : NEG_);
  }
  float mn = fmaxf(ms, sgm);
  float al = __expf(ms - mn);
  float pg = __expf(sgm - mn);
  float inv = 1.f / (ls*al + pg);
  u16* obase = aout + ((ll)(b*S_ + q0 + wq + lane15))*DM_ + h*64;
  #pragma unroll
  for(int nt=0;nt<4;nt++){
    float4 v0q = *(const float4*)&v0f[nt*16 + quad*4];
    float v0a[4] = {v0q.x, v0q.y, v0q.z, v0q.w};
    u16 o[4];
    #pragma unroll
    for(int r=0;r<4;r++) o[r] = f2b((ao[nt][r]*al + pg*v0a[r]) * inv);
    uint2 w;
    w.x = (u32)o[0] | ((u32)o[1]<<16);
    w.y = (u32)o[2] | ((u32)o[3]<<16);
    *(uint2*)&obase[nt*16 + quad*4] = w;
  }
}

// ---------------- global-token attention, stage 1: per-chunk partials ----------------
// part[b][h][chunk] = { m_c, l_c, o_c[64] }  (66 floats)
__global__ __launch_bounds__(256) void k_gattn1(const float* __restrict__ qg, const u16* __restrict__ kg,
    const u16* __restrict__ vg, const int* __restrict__ am, float* __restrict__ part){
  int ck = blockIdx.x, h = blockIdx.y, b = blockIdx.z;
  int t = threadIdx.x;
  __shared__ float s4[4];
  __shared__ float qgs[64];
  __shared__ float ps[256];
  __shared__ float obuf[4][64];
  if(t < 64) qgs[t] = qg[b*DM_ + h*64 + t];
  __syncthreads();
  int s = ck*256 + t;
  const uint4* kr = (const uint4*)(kg + (ll)(b*S_+s)*QS_ + h*64);
  float d = 0.f;
  #pragma unroll
  for(int g=0; g<8; g++){
    float tf[8]; unp8(kr[g], tf);
    #pragma unroll
    for(int e=0;e<8;e++) d = fmaf(qgs[g*8+e], tf[e], d);
  }
  float sc = (am[b*S_+s] > 0) ? d*0.125f : NEG_;
  float m_c = bmax256(sc, s4);
  float p = __expf(sc - m_c);
  float l_c = bsum256(p, s4);
  ps[t] = p;
  __syncthreads();
  // o_c[d] = sum_t p_t * v[t][d]; thread (grp,dd) covers 64 positions of group grp
  int dd = t & 63, grp = t >> 6;
  float acc = 0.f;
  const u16* vbase = vg + (ll)(b*S_ + ck*256 + grp*64)*QS_ + h*64 + dd;
  #pragma unroll 8
  for(int j=0;j<64;j++)
    acc = fmaf(ps[grp*64+j], b2f(vbase[(ll)j*QS_]), acc);
  obuf[grp][dd] = acc;
  __syncthreads();
  if(t < 64){
    float o = obuf[0][t] + obuf[1][t] + obuf[2][t] + obuf[3][t];
    float* pp = part + ((ll)(b*H_+h)*GC_ + ck)*66;
    if(t == 0){ pp[0] = m_c; pp[1] = l_c; }
    pp[2+t] = o;
  }
}

// ---------------- global-token attention, stage 2: combine chunks -> aout row 0 ----------------
__global__ void k_gattn2(const float* __restrict__ part, u16* __restrict__ aout){
  int h = blockIdx.x, b = blockIdx.y;
  int t = threadIdx.x;   // 64 threads
  const float* pp = part + ((ll)(b*H_+h)*GC_)*66;
  float m = -INFINITY;
  #pragma unroll
  for(int c=0;c<GC_;c++) m = fmaxf(m, pp[c*66]);
  float l = 0.f, o = 0.f;
  #pragma unroll
  for(int c=0;c<GC_;c++){
    float w = __expf(pp[c*66] - m);
    l += pp[c*66+1]*w;
    o += pp[c*66+2+t]*w;
  }
  aout[(ll)(b*S_)*DM_ + h*64 + t] = f2b(o/l);
}

// ---------------- classifier ----------------
__global__ __launch_bounds__(256) void k_cls(const float* __restrict__ x, const float* __restrict__ Wc,
    const float* __restrict__ bc, void* out, const int* flag){
  __shared__ float s4[4];
  int t = threadIdx.x;
  float a00=0,a01=0,a10=0,a11=0;
  for(int k=t;k<DM_;k+=256){
    float w0 = Wc[k*2], w1 = Wc[k*2+1];
    float x0 = x[k];
    float x1 = x[(ll)S_*DM_ + k];
    a00 = fmaf(x0,w0,a00); a01 = fmaf(x0,w1,a01);
    a10 = fmaf(x1,w0,a10); a11 = fmaf(x1,w1,a11);
  }
  float r00 = bsum256(a00,s4);
  float r01 = bsum256(a01,s4);
  float r10 = bsum256(a10,s4);
  float r11 = bsum256(a11,s4);
  if(t==0){
    float o[4] = {r00+bc[0], r01+bc[1], r10+bc[0], r11+bc[1]};
    if(*flag){
      __hip_bfloat16* ob = (__hip_bfloat16*)out;
      for(int i=0;i<4;i++) ob[i] = __float2bfloat16(o[i]);
    } else {
      float* of = (float*)out;
      for(int i=0;i<4;i++) of[i] = o[i];
    }
  }
}

extern "C" void kernel_launch(void* const* d_in, const int* in_sizes, int n_in,
                              void* d_out, int out_size, void* d_ws, size_t ws_size,
                              hipStream_t stream){
  char* wsb = (char*)d_ws;
  size_t off = 0;
  auto alloc = [&](size_t bytes)->size_t{ off = (off + 255) & ~(size_t)255; size_t r = off; off += bytes; return r; };
  const size_t TOK = (size_t)B_*S_;
  size_t P_flag = alloc(16);
  size_t P_pos  = alloc((size_t)S_*DM_*4);
  size_t P_les  = alloc(DM_*4), P_leb = alloc(DM_*4);
  size_t P_bqkv = alloc((size_t)L_*QS_*4);
  size_t P_bqg  = alloc((size_t)L_*DM_*4);
  size_t P_bo   = alloc((size_t)L_*DM_*4);
  size_t P_b1   = alloc((size_t)L_*DFF_*4);
  size_t P_b2   = alloc((size_t)L_*DM_*4);
  size_t P_l1s  = alloc((size_t)L_*DM_*4), P_l1b = alloc((size_t)L_*DM_*4);
  size_t P_l2s  = alloc((size_t)L_*DM_*4), P_l2b = alloc((size_t)L_*DM_*4);
  size_t P_Wc   = alloc(DM_*2*4), P_bc = alloc(64);
  size_t P_qgb  = alloc((size_t)B_*DM_*4);
  size_t P_part = alloc((size_t)B_*H_*GC_*66*4);
  size_t P_Wqkvt= alloc((size_t)L_*QS_*DM_*2);
  size_t P_Wqgt = alloc((size_t)L_*DM_*DM_*2);
  size_t P_Wot  = alloc((size_t)L_*DM_*DM_*2);
  size_t P_W1t  = alloc((size_t)L_*DM_*DFF_*2);
  size_t P_W2t  = alloc((size_t)L_*DFF_*DM_*2);
  size_t P_x    = alloc(TOK*DM_*4);
  size_t P_tmp  = alloc(TOK*DM_*4);
  size_t P_xb   = alloc(TOK*DM_*2);
  size_t P_qkv  = alloc(TOK*QS_*2);
  size_t P_aout = alloc(TOK*DM_*2);
  size_t P_h    = alloc(TOK*DFF_*2);

  int* flag = (int*)(wsb + P_flag);
  #define FP(o) ((float*)(wsb + (o)))
  #define HP(o) ((u16*)(wsb + (o)))

  k_detect<<<1,1,0,stream>>>(d_in[4], flag);

  k_cvt<<<2048,256,0,stream>>>(d_in[3], 0, FP(P_pos), S_*DM_, flag);

  {
    CvtArgs ca{};
    int ns = 0;
    auto addcv = [&](int idx, size_t dstoff, int soff, int nelem){
      ca.src[ns] = d_in[idx]; ca.dst[ns] = FP(dstoff); ca.soff[ns] = soff; ca.n[ns] = nelem; ns++;
    };
    addcv(4, P_les, 0, DM_); addcv(5, P_leb, 0, DM_);
    addcv(28, P_Wc, 0, DM_*2); addcv(29, P_bc, 0, 2);
    const int bidx[5] = {7,9,11,15,17};
    for(int l=0;l<L_;l++){
      for(int s=0;s<5;s++) addcv(bidx[s], P_bqkv + ((size_t)l*QS_ + s*DM_)*4, l*DM_, DM_);
      addcv(13, P_bqg + (size_t)l*DM_*4,  l*DM_,  DM_);
      addcv(19, P_bo  + (size_t)l*DM_*4,  l*DM_,  DM_);
      addcv(23, P_b1  + (size_t)l*DFF_*4, l*DFF_, DFF_);
      addcv(25, P_b2  + (size_t)l*DM_*4,  l*DM_,  DM_);
      addcv(20, P_l1s + (size_t)l*DM_*4,  l*DM_,  DM_);
      addcv(21, P_l1b + (size_t)l*DM_*4,  l*DM_,  DM_);
      addcv(26, P_l2s + (size_t)l*DM_*4,  l*DM_,  DM_);
      addcv(27, P_l2b + (size_t)l*DM_*4,  l*DM_,  DM_);
    }
    for(int s2=ns; s2<32; s2++){ ca.src[s2]=d_in[4]; ca.dst[s2]=FP(P_les); ca.soff[s2]=0; ca.n[s2]=0; }
    k_cvts<<<dim3(12, ns),256,0,stream>>>(ca, flag);
  }

  {
    TwArgs ta{};
    int nt_ = 0;
    const int widx[5] = {6,8,10,14,16};
    for(int l=0;l<L_;l++){
      for(int s=0;s<5;s++){
        ta.src[nt_] = d_in[widx[s]]; ta.soff[nt_] = (ll)l*DM_*DM_;
        ta.dst[nt_] = HP(P_Wqkvt) + (size_t)l*QS_*DM_ + (size_t)s*DM_*DM_; nt_++;
      }
      ta.src[nt_] = d_in[12]; ta.soff[nt_] = (ll)l*DM_*DM_;
      ta.dst[nt_] = HP(P_Wqgt) + (size_t)l*DM_*DM_; nt_++;
      ta.src[nt_] = d_in[18]; ta.soff[nt_] = (ll)l*DM_*DM_;
      ta.dst[nt_] = HP(P_Wot) + (size_t)l*DM_*DM_; nt_++;
    }
    k_tws<<<dim3(24,24,14),256,0,stream>>>(ta, flag);
  }
  for(int l=0;l<L_;l++){
    k_tw<<<dim3(DFF_/32, DM_/32),256,0,stream>>>(d_in[22], (ll)l*DM_*DFF_,
        HP(P_W1t) + (size_t)l*DFF_*DM_, DM_, DFF_, flag);
    k_tw<<<dim3(DM_/32, DFF_/32),256,0,stream>>>(d_in[24], (ll)l*DFF_*DM_,
        HP(P_W2t) + (size_t)l*DM_*DFF_, DFF_, DM_, flag);
  }

  const int* am = (const int*)d_in[1];
  k_embed<<<(int)TOK,256,0,stream>>>((const int*)d_in[0], d_in[2], FP(P_pos), FP(P_les), FP(P_leb),
                                     FP(P_x), HP(P_xb), flag);
  const int GM = (int)TOK/128;   // 64 M-tiles
  for(int l=0;l<L_;l++){
    const u16* Wqkvt_l = HP(P_Wqkvt) + (size_t)l*QS_*DM_;
    k_mm<0><<<(QS_/128)*GM,256,0,stream>>>(HP(P_xb), Wqkvt_l, FP(P_bqkv) + (size_t)l*QS_,
        HP(P_qkv), (int)TOK, QS_, DM_);
    k_qg<<<dim3(3,B_),256,0,stream>>>(FP(P_x), HP(P_Wqgt) + (size_t)l*DM_*DM_, FP(P_bqg) + (size_t)l*DM_, FP(P_qgb));
    k_band<<<dim3(S_/QB_,H_,B_),256,0,stream>>>(HP(P_qkv), HP(P_qkv)+DM_, HP(P_qkv)+2*DM_, am, HP(P_aout));
    k_gattn1<<<dim3(GC_,H_,B_),256,0,stream>>>(FP(P_qgb), HP(P_qkv)+3*DM_, HP(P_qkv)+4*DM_, am, FP(P_part));
    k_gattn2<<<dim3(H_,B_),64,0,stream>>>(FP(P_part), HP(P_aout));
    k_mm<1><<<(DM_/128)*GM,256,0,stream>>>(HP(P_aout), HP(P_Wot) + (size_t)l*DM_*DM_,
        FP(P_bo) + (size_t)l*DM_, FP(P_tmp), (int)TOK, DM_, DM_);
    k_rln<<<(int)TOK,256,0,stream>>>(FP(P_x), FP(P_tmp), FP(P_l1s) + (size_t)l*DM_, FP(P_l1b) + (size_t)l*DM_, HP(P_xb));
    k_mm<2><<<(DFF_/128)*GM,256,0,stream>>>(HP(P_xb), HP(P_W1t) + (size_t)l*DFF_*DM_,
        FP(P_b1) + (size_t)l*DFF_, HP(P_h), (int)TOK, DFF_, DM_);
    k_mm<1><<<(DM_/128)*GM,256,0,stream>>>(HP(P_h), HP(P_W2t) + (size_t)l*DM_*DFF_,
        FP(P_b2) + (size_t)l*DM_, FP(P_tmp), (int)TOK, DM_, DFF_);
    k_rln<<<(int)TOK,256,0,stream>>>(FP(P_x), FP(P_tmp), FP(P_l2s) + (size_t)l*DM_, FP(P_l2b) + (size_t)l*DM_, HP(P_xb));
  }
  k_cls<<<1,256,0,stream>>>(FP(P_x), FP(P_Wc), FP(P_bc), d_out, flag);
}